// Round 8
// baseline (844.289 us; speedup 1.0000x reference)
//
#include <hip/hip_runtime.h>

#define H 128
#define OUTD 10

typedef short bf16x8 __attribute__((ext_vector_type(8)));
typedef float f32x4 __attribute__((ext_vector_type(4)));

// ---------- bf16 helpers ----------
__device__ __forceinline__ unsigned short f2bf(float x) {
  unsigned u = __float_as_uint(x);
  u += 0x7fffu + ((u >> 16) & 1u);  // RNE
  return (unsigned short)(u >> 16);
}
__device__ __forceinline__ unsigned pack2bf(float a, float b) {
  return (unsigned)f2bf(a) | ((unsigned)f2bf(b) << 16);
}
__device__ __forceinline__ float bf2f(unsigned short u) {
  return __uint_as_float(((unsigned)u) << 16);
}
__device__ __forceinline__ float bflo(unsigned u) { return __uint_as_float(u << 16); }
__device__ __forceinline__ float bfhi(unsigned u) { return __uint_as_float(u & 0xffff0000u); }

// ---------- ordered-float encoding for atomic max ----------
__device__ __forceinline__ unsigned fenc(float x) {
  unsigned u = __float_as_uint(x);
  return (u & 0x80000000u) ? ~u : (u | 0x80000000u);
}
__device__ __forceinline__ float fdec(unsigned u) {
  u = (u & 0x80000000u) ? (u & 0x7fffffffu) : ~u;
  return __uint_as_float(u);
}

// ---------- weight prep: 8 matrices -> bf16 transposed [j][k] ----------
__global__ void prep_w(const float* __restrict__ gcnW, const float* __restrict__ gatW,
                       const float* __restrict__ ecW1, const float* __restrict__ ecW2,
                       const float* __restrict__ ginW1, const float* __restrict__ ginW2,
                       const float* __restrict__ gtW1, unsigned short* __restrict__ WT) {
  int f = blockIdx.x * 256 + threadIdx.x;
  if (f >= 8 * 16384) return;
  int m = f >> 14, idx = f & 16383;
  int j = idx >> 7, k = idx & 127;
  int src = k * 128 + j;
  float v;
  switch (m) {
    case 0: v = gcnW[src]; break;
    case 1: v = gatW[src]; break;
    case 2: v = ecW1[src] - ecW1[16384 + src]; break;  // Wa = top - bot
    case 3: v = ecW1[16384 + src]; break;              // Wb
    case 4: v = ecW2[src]; break;
    case 5: v = ginW1[src]; break;
    case 6: v = ginW2[src]; break;
    default: v = gtW1[src]; break;
  }
  WT[f] = f2bf(v);
}

// ---------- MFMA dense [n,128]@[128,128], W^T bf16 in global (L1), bf16 out ----------
template <int IN_BF, int RELU, int BIAS>
__global__ __launch_bounds__(256) void dense_mfma(const void* __restrict__ Xv,
                                                  const unsigned short* __restrict__ WT,
                                                  const float* __restrict__ bias,
                                                  unsigned short* __restrict__ Y, int n) {
  __shared__ unsigned short tile[64][136];
  const int tid = threadIdx.x, lane = tid & 63, wave = tid >> 6;
  const int jl = lane & 15, kg = lane >> 4;
  const int base = blockIdx.x * 64;
  if (base >= n) return;
  const int nr = min(64, n - base);
  if (IN_BF) {
    const uint4* X4 = (const uint4*)Xv;
#pragma unroll
    for (int it = 0; it < 4; ++it) {
      int f = it * 256 + tid, r = f >> 4, q = f & 15;
      if (r < nr) *(uint4*)&tile[r][q * 8] = X4[(size_t)(base + r) * 16 + q];
    }
  } else {
    const float* X = (const float*)Xv;
#pragma unroll
    for (int it = 0; it < 16; ++it) {
      int f = it * 256 + tid, r = f >> 6, kp = f & 63;
      if (r < nr) {
        float2 v = *(const float2*)&X[(size_t)(base + r) * H + 2 * kp];
        *(unsigned*)&tile[r][2 * kp] = pack2bf(v.x, v.y);
      }
    }
  }
  __syncthreads();
  bf16x8 afrag[4];
#pragma unroll
  for (int kk = 0; kk < 4; ++kk)
    afrag[kk] = *(const bf16x8*)&tile[wave * 16 + jl][kk * 32 + kg * 8];
  f32x4 acc[8];
#pragma unroll
  for (int jt = 0; jt < 8; ++jt) {
    f32x4 c = {0.f, 0.f, 0.f, 0.f};
#pragma unroll
    for (int kk = 0; kk < 4; ++kk) {
      bf16x8 bf = *(const bf16x8*)&WT[(size_t)(jt * 16 + jl) * H + kk * 32 + kg * 8];
      c = __builtin_amdgcn_mfma_f32_16x16x32_bf16(afrag[kk], bf, c, 0, 0, 0);
    }
    if (BIAS) {
      float bb = bias[jt * 16 + jl];
#pragma unroll
      for (int r = 0; r < 4; ++r) c[r] += bb;
    }
    if (RELU) {
#pragma unroll
      for (int r = 0; r < 4; ++r) c[r] = fmaxf(c[r], 0.f);
    }
    acc[jt] = c;
  }
  __syncthreads();
#pragma unroll
  for (int jt = 0; jt < 8; ++jt)
#pragma unroll
    for (int r = 0; r < 4; ++r) tile[wave * 16 + kg * 4 + r][jt * 16 + jl] = f2bf(acc[jt][r]);
  __syncthreads();
#pragma unroll
  for (int it = 0; it < 4; ++it) {
    int f = it * 256 + tid, r = f >> 4, q = f & 15;
    if (r < nr) *(uint4*)&Y[(size_t)(base + r) * H + q * 8] = *(const uint4*)&tile[r][q * 8];
  }
}

// ---------- dual dense: Y1 = X@W1, Y2 = X@W2 + b2 (shared X staging) ----------
__global__ __launch_bounds__(256) void dense_dual(const unsigned short* __restrict__ X,
                                                  const unsigned short* __restrict__ WT1,
                                                  const unsigned short* __restrict__ WT2,
                                                  const float* __restrict__ bias2,
                                                  unsigned short* __restrict__ Y1,
                                                  unsigned short* __restrict__ Y2, int n) {
  __shared__ unsigned short tile[64][136];
  const int tid = threadIdx.x, lane = tid & 63, wave = tid >> 6;
  const int jl = lane & 15, kg = lane >> 4;
  const int base = blockIdx.x * 64;
  if (base >= n) return;
  const int nr = min(64, n - base);
  const uint4* X4 = (const uint4*)X;
#pragma unroll
  for (int it = 0; it < 4; ++it) {
    int f = it * 256 + tid, r = f >> 4, q = f & 15;
    if (r < nr) *(uint4*)&tile[r][q * 8] = X4[(size_t)(base + r) * 16 + q];
  }
  __syncthreads();
  bf16x8 afrag[4];
#pragma unroll
  for (int kk = 0; kk < 4; ++kk)
    afrag[kk] = *(const bf16x8*)&tile[wave * 16 + jl][kk * 32 + kg * 8];
  f32x4 acc[8];
#pragma unroll
  for (int jt = 0; jt < 8; ++jt) {
    f32x4 c = {0.f, 0.f, 0.f, 0.f};
#pragma unroll
    for (int kk = 0; kk < 4; ++kk) {
      bf16x8 bf = *(const bf16x8*)&WT1[(size_t)(jt * 16 + jl) * H + kk * 32 + kg * 8];
      c = __builtin_amdgcn_mfma_f32_16x16x32_bf16(afrag[kk], bf, c, 0, 0, 0);
    }
    acc[jt] = c;
  }
  __syncthreads();
#pragma unroll
  for (int jt = 0; jt < 8; ++jt)
#pragma unroll
    for (int r = 0; r < 4; ++r) tile[wave * 16 + kg * 4 + r][jt * 16 + jl] = f2bf(acc[jt][r]);
  __syncthreads();
#pragma unroll
  for (int it = 0; it < 4; ++it) {
    int f = it * 256 + tid, r = f >> 4, q = f & 15;
    if (r < nr) *(uint4*)&Y1[(size_t)(base + r) * H + q * 8] = *(const uint4*)&tile[r][q * 8];
  }
  __syncthreads();
#pragma unroll
  for (int jt = 0; jt < 8; ++jt) {
    f32x4 c = {0.f, 0.f, 0.f, 0.f};
#pragma unroll
    for (int kk = 0; kk < 4; ++kk) {
      bf16x8 bf = *(const bf16x8*)&WT2[(size_t)(jt * 16 + jl) * H + kk * 32 + kg * 8];
      c = __builtin_amdgcn_mfma_f32_16x16x32_bf16(afrag[kk], bf, c, 0, 0, 0);
    }
    float bb = bias2[jt * 16 + jl];
#pragma unroll
    for (int r = 0; r < 4; ++r) c[r] += bb;
    acc[jt] = c;
  }
  __syncthreads();
#pragma unroll
  for (int jt = 0; jt < 8; ++jt)
#pragma unroll
    for (int r = 0; r < 4; ++r) tile[wave * 16 + kg * 4 + r][jt * 16 + jl] = f2bf(acc[jt][r]);
  __syncthreads();
#pragma unroll
  for (int it = 0; it < 4; ++it) {
    int f = it * 256 + tid, r = f >> 4, q = f & 15;
    if (r < nr) *(uint4*)&Y2[(size_t)(base + r) * H + q * 8] = *(const uint4*)&tile[r][q * 8];
  }
}

// ---------- chained dense (GIN): Y = relu(relu(X@W1+b1)@W2+b2) ----------
__global__ __launch_bounds__(256) void dense_chain(const unsigned short* __restrict__ X,
                                                   const unsigned short* __restrict__ WT1,
                                                   const float* __restrict__ b1,
                                                   const unsigned short* __restrict__ WT2,
                                                   const float* __restrict__ b2,
                                                   unsigned short* __restrict__ Y, int n) {
  __shared__ unsigned short tile[64][136];
  const int tid = threadIdx.x, lane = tid & 63, wave = tid >> 6;
  const int jl = lane & 15, kg = lane >> 4;
  const int base = blockIdx.x * 64;
  if (base >= n) return;
  const int nr = min(64, n - base);
  const uint4* X4 = (const uint4*)X;
#pragma unroll
  for (int it = 0; it < 4; ++it) {
    int f = it * 256 + tid, r = f >> 4, q = f & 15;
    if (r < nr) *(uint4*)&tile[r][q * 8] = X4[(size_t)(base + r) * 16 + q];
  }
  __syncthreads();
  bf16x8 af[4];
#pragma unroll
  for (int kk = 0; kk < 4; ++kk) af[kk] = *(const bf16x8*)&tile[wave * 16 + jl][kk * 32 + kg * 8];
  f32x4 acc[8];
#pragma unroll
  for (int jt = 0; jt < 8; ++jt) {
    f32x4 c = {0.f, 0.f, 0.f, 0.f};
#pragma unroll
    for (int kk = 0; kk < 4; ++kk) {
      bf16x8 bf = *(const bf16x8*)&WT1[(size_t)(jt * 16 + jl) * H + kk * 32 + kg * 8];
      c = __builtin_amdgcn_mfma_f32_16x16x32_bf16(af[kk], bf, c, 0, 0, 0);
    }
    float bb = b1[jt * 16 + jl];
#pragma unroll
    for (int r = 0; r < 4; ++r) c[r] = fmaxf(c[r] + bb, 0.f);
    acc[jt] = c;
  }
  __syncthreads();
#pragma unroll
  for (int jt = 0; jt < 8; ++jt)
#pragma unroll
    for (int r = 0; r < 4; ++r) tile[wave * 16 + kg * 4 + r][jt * 16 + jl] = f2bf(acc[jt][r]);
  __syncthreads();
#pragma unroll
  for (int kk = 0; kk < 4; ++kk) af[kk] = *(const bf16x8*)&tile[wave * 16 + jl][kk * 32 + kg * 8];
#pragma unroll
  for (int jt = 0; jt < 8; ++jt) {
    f32x4 c = {0.f, 0.f, 0.f, 0.f};
#pragma unroll
    for (int kk = 0; kk < 4; ++kk) {
      bf16x8 bf = *(const bf16x8*)&WT2[(size_t)(jt * 16 + jl) * H + kk * 32 + kg * 8];
      c = __builtin_amdgcn_mfma_f32_16x16x32_bf16(af[kk], bf, c, 0, 0, 0);
    }
    float bb = b2[jt * 16 + jl];
#pragma unroll
    for (int r = 0; r < 4; ++r) c[r] = fmaxf(c[r] + bb, 0.f);
    acc[jt] = c;
  }
  __syncthreads();
#pragma unroll
  for (int jt = 0; jt < 8; ++jt)
#pragma unroll
    for (int r = 0; r < 4; ++r) tile[wave * 16 + kg * 4 + r][jt * 16 + jl] = f2bf(acc[jt][r]);
  __syncthreads();
#pragma unroll
  for (int it = 0; it < 4; ++it) {
    int f = it * 256 + tid, r = f >> 4, q = f & 15;
    if (r < nr) *(uint4*)&Y[(size_t)(base + r) * H + q * 8] = *(const uint4*)&tile[r][q * 8];
  }
}

// ---------- gate dense: gate = relu(X@W1+b1) . w2 + b2 ----------
__global__ __launch_bounds__(256) void dense_gate(const unsigned short* __restrict__ X,
                                                  const unsigned short* __restrict__ WT,
                                                  const float* __restrict__ b1,
                                                  const float* __restrict__ w2,
                                                  const float* __restrict__ b2,
                                                  float* __restrict__ gate, int n) {
  __shared__ unsigned short tile[64][136];
  const int tid = threadIdx.x, lane = tid & 63, wave = tid >> 6;
  const int jl = lane & 15, kg = lane >> 4;
  const int base = blockIdx.x * 64;
  if (base >= n) return;
  const int nr = min(64, n - base);
  const uint4* X4 = (const uint4*)X;
#pragma unroll
  for (int it = 0; it < 4; ++it) {
    int f = it * 256 + tid, r = f >> 4, q = f & 15;
    if (r < nr) *(uint4*)&tile[r][q * 8] = X4[(size_t)(base + r) * 16 + q];
  }
  __syncthreads();
  bf16x8 af[4];
#pragma unroll
  for (int kk = 0; kk < 4; ++kk) af[kk] = *(const bf16x8*)&tile[wave * 16 + jl][kk * 32 + kg * 8];
  float p0 = 0.f, p1 = 0.f, p2 = 0.f, p3 = 0.f;
#pragma unroll
  for (int jt = 0; jt < 8; ++jt) {
    f32x4 c = {0.f, 0.f, 0.f, 0.f};
#pragma unroll
    for (int kk = 0; kk < 4; ++kk) {
      bf16x8 bf = *(const bf16x8*)&WT[(size_t)(jt * 16 + jl) * H + kk * 32 + kg * 8];
      c = __builtin_amdgcn_mfma_f32_16x16x32_bf16(af[kk], bf, c, 0, 0, 0);
    }
    float bb = b1[jt * 16 + jl];
    float wv = w2[jt * 16 + jl];
    p0 = fmaf(fmaxf(c[0] + bb, 0.f), wv, p0);
    p1 = fmaf(fmaxf(c[1] + bb, 0.f), wv, p1);
    p2 = fmaf(fmaxf(c[2] + bb, 0.f), wv, p2);
    p3 = fmaf(fmaxf(c[3] + bb, 0.f), wv, p3);
  }
#pragma unroll
  for (int off = 1; off <= 8; off <<= 1) {
    p0 += __shfl_xor(p0, off);
    p1 += __shfl_xor(p1, off);
    p2 += __shfl_xor(p2, off);
    p3 += __shfl_xor(p3, off);
  }
  if (jl == 0) {
    float bb2 = b2[0];
    int row = wave * 16 + kg * 4;
    if (row + 0 < nr) gate[base + row + 0] = p0 + bb2;
    if (row + 1 < nr) gate[base + row + 1] = p1 + bb2;
    if (row + 2 < nr) gate[base + row + 2] = p2 + bb2;
    if (row + 3 < nr) gate[base + row + 3] = p3 + bb2;
  }
}

// ---------- CSR build ----------
__global__ void zero_int(int* p, int n) {
  int i = blockIdx.x * 256 + threadIdx.x;
  if (i < n) p[i] = 0;
}
__global__ void csr_count(const int* __restrict__ ei, int* __restrict__ cnt, int E) {
  int e = blockIdx.x * 256 + threadIdx.x;
  if (e < E) atomicAdd(&cnt[ei[(size_t)E + e]], 1);
}
__global__ __launch_bounds__(1024) void scan50k(const int* __restrict__ cnt,
                                                int* __restrict__ row_ptr, int n) {
  __shared__ int ls[1024];
  int t = threadIdx.x;
  int chunk = (n + 1023) >> 10;
  int a = t * chunk;
  if (a > n) a = n;
  int b = a + chunk;
  if (b > n) b = n;
  int s = 0;
  for (int i = a; i < b; ++i) s += cnt[i];
  ls[t] = s;
  __syncthreads();
  for (int off = 1; off < 1024; off <<= 1) {
    int v = (t >= off) ? ls[t - off] : 0;
    __syncthreads();
    ls[t] += v;
    __syncthreads();
  }
  int run = (t > 0) ? ls[t - 1] : 0;
  for (int i = a; i < b; ++i) {
    row_ptr[i] = run;
    run += cnt[i];
  }
  if (t == 1023) row_ptr[n] = ls[1023];
}
__global__ void copy_int(const int* __restrict__ a, int* __restrict__ b, int n) {
  int i = blockIdx.x * 256 + threadIdx.x;
  if (i < n) b[i] = a[i];
}
__global__ void csr_fill(const int* __restrict__ ei, int* __restrict__ cursor,
                         int* __restrict__ csr_src, int* __restrict__ csr_dst, int E) {
  int e = blockIdx.x * 256 + threadIdx.x;
  if (e >= E) return;
  int s = ei[e], d = ei[(size_t)E + e];
  int p = atomicAdd(&cursor[d], 1);
  csr_src[p] = s;
  csr_dst[p] = d;
}
__global__ void dinv_kernel(const int* __restrict__ row_ptr, float* __restrict__ dinv, int n) {
  int i = blockIdx.x * 256 + threadIdx.x;
  if (i < n) dinv[i] = rsqrtf((float)(1 + row_ptr[i + 1] - row_ptr[i]));
}
__global__ void fill_u32(unsigned* p, unsigned v, size_t n) {
  size_t i = (size_t)blockIdx.x * 256 + threadIdx.x;
  if (i < n) p[i] = v;
}

// ---------- GCN gather: wave per node, 8x unrolled ----------
__global__ __launch_bounds__(256) void gcn_gather(const unsigned short* __restrict__ h,
                                                  const float* __restrict__ dinv,
                                                  const int* __restrict__ row_ptr,
                                                  const int* __restrict__ csr_src,
                                                  const float* __restrict__ bias,
                                                  unsigned short* __restrict__ out, int n) {
  int node = blockIdx.x * 4 + (threadIdx.x >> 6);
  int lane = threadIdx.x & 63;
  if (node >= n) return;
  const unsigned* hu = (const unsigned*)h;
  float di = dinv[node];
  unsigned v = hu[(size_t)node * 64 + lane];
  float t0 = bflo(v) * di, t1 = bfhi(v) * di;
  int a = row_ptr[node], b = row_ptr[node + 1];
  int e = a;
  for (; e + 8 <= b; e += 8) {
    int sx[8];
#pragma unroll
    for (int i = 0; i < 8; ++i) sx[i] = csr_src[e + i];
    unsigned w[8];
    float dd[8];
#pragma unroll
    for (int i = 0; i < 8; ++i) w[i] = hu[(size_t)sx[i] * 64 + lane];
#pragma unroll
    for (int i = 0; i < 8; ++i) dd[i] = dinv[sx[i]];
#pragma unroll
    for (int i = 0; i < 8; ++i) {
      t0 = fmaf(bflo(w[i]), dd[i], t0);
      t1 = fmaf(bfhi(w[i]), dd[i], t1);
    }
  }
  for (; e < b; ++e) {
    int s = csr_src[e];
    float ds = dinv[s];
    unsigned w = hu[(size_t)s * 64 + lane];
    t0 = fmaf(bflo(w), ds, t0);
    t1 = fmaf(bfhi(w), ds, t1);
  }
  float y0 = fmaxf(fmaf(t0, di, bias[lane * 2]), 0.f);
  float y1 = fmaxf(fmaf(t1, di, bias[lane * 2 + 1]), 0.f);
  ((unsigned*)out)[(size_t)node * 64 + lane] = pack2bf(y0, y1);
}

__global__ void att_pre(const unsigned short* __restrict__ g, const float* __restrict__ attS,
                        const float* __restrict__ attD, float* __restrict__ asrc,
                        float* __restrict__ adst, int n) {
  int t = blockIdx.x * 256 + threadIdx.x;
  if (t >= n * 4) return;
  int i = t >> 2, hd = t & 3;
  const unsigned* gr = (const unsigned*)(g + (size_t)i * H + hd * 32);
  float s1 = 0.f, s2 = 0.f;
#pragma unroll
  for (int p = 0; p < 16; ++p) {
    unsigned u = gr[p];
    float a = bflo(u), b = bfhi(u);
    s1 = fmaf(a, attS[hd * 32 + 2 * p], fmaf(b, attS[hd * 32 + 2 * p + 1], s1));
    s2 = fmaf(a, attD[hd * 32 + 2 * p], fmaf(b, attD[hd * 32 + 2 * p + 1], s2));
  }
  asrc[t] = s1;
  adst[t] = s2;
}

__device__ __forceinline__ float lrelu_exp(float v) {
  v = v > 0.f ? v : 0.2f * v;
  return __expf(v);
}

// ---------- GAT gather: wave per node, 8x unrolled ----------
__global__ __launch_bounds__(256) void gat_gather(const unsigned short* __restrict__ g,
                                                  const float* __restrict__ asrc,
                                                  const float* __restrict__ adst,
                                                  const int* __restrict__ row_ptr,
                                                  const int* __restrict__ csr_src,
                                                  const float* __restrict__ bias,
                                                  unsigned short* __restrict__ out, int n) {
  int node = blockIdx.x * 4 + (threadIdx.x >> 6);
  int lane = threadIdx.x & 63;
  if (node >= n) return;
  const int hd = lane >> 4;
  const unsigned* gu = (const unsigned*)g;
  float adc = adst[node * 4 + hd];
  float w = lrelu_exp(asrc[node * 4 + hd] + adc);
  unsigned u = gu[(size_t)node * 64 + lane];
  float acc0 = w * bflo(u), acc1 = w * bfhi(u), wsum = w;
  int a = row_ptr[node], b = row_ptr[node + 1];
  int e = a;
  for (; e + 8 <= b; e += 8) {
    int sx[8];
#pragma unroll
    for (int i = 0; i < 8; ++i) sx[i] = csr_src[e + i];
    unsigned uu[8];
#pragma unroll
    for (int i = 0; i < 8; ++i) uu[i] = gu[(size_t)sx[i] * 64 + lane];
    float ww[8];
#pragma unroll
    for (int i = 0; i < 8; ++i) ww[i] = lrelu_exp(asrc[sx[i] * 4 + hd] + adc);
#pragma unroll
    for (int i = 0; i < 8; ++i) {
      acc0 = fmaf(ww[i], bflo(uu[i]), acc0);
      acc1 = fmaf(ww[i], bfhi(uu[i]), acc1);
      wsum += ww[i];
    }
  }
  for (; e < b; ++e) {
    int s = csr_src[e];
    unsigned us = gu[(size_t)s * 64 + lane];
    float we = lrelu_exp(asrc[s * 4 + hd] + adc);
    acc0 = fmaf(we, bflo(us), acc0);
    acc1 = fmaf(we, bfhi(us), acc1);
    wsum += we;
  }
  float inv = 1.f / (wsum + 1e-16f);
  float r0 = acc0 * inv + bias[2 * lane];
  float r1 = acc1 * inv + bias[2 * lane + 1];
  r0 = r0 > 0.f ? r0 : expm1f(r0);
  r1 = r1 > 0.f ? r1 : expm1f(r1);
  ((unsigned*)out)[(size_t)node * 64 + lane] = pack2bf(r0, r1);
}

// ---------- EdgeConv: pipelined tile MFMA + LDS slot privatization ----------
__global__ __launch_bounds__(256) void edgeconv_tile(const unsigned short* __restrict__ A,
                                                     const unsigned short* __restrict__ Bm,
                                                     const int* __restrict__ csr_src,
                                                     const int* __restrict__ csr_dst,
                                                     const int* __restrict__ row_ptr,
                                                     const unsigned short* __restrict__ W2T,
                                                     const float* __restrict__ b2,
                                                     unsigned* __restrict__ hec, int E) {
  __shared__ unsigned short buf[2][64][140];
  __shared__ int dbuf[2][64];
  __shared__ unsigned slots[16][128];  // per-tile node-slot max accumulators (fenc)
  __shared__ int slotmap[2][64];
  __shared__ int slot_dst2[2][16];
  __shared__ int slot_comp2[2][16];
  __shared__ int nslots2[2];
  const int tid = threadIdx.x, lane = tid & 63, wave = tid >> 6;
  const int jl = lane & 15, kg = lane >> 4;
  const int srow = tid >> 2, sq = tid & 3;
  float b2v[8];
#pragma unroll
  for (int jt = 0; jt < 8; ++jt) b2v[jt] = b2[jt * 16 + jl];
  const float b2c = b2[tid & 127];  // for flush (col = tid&127)

  for (int i = tid; i < 16 * 128; i += 256) ((unsigned*)slots)[i] = 0;

  const int tiles = (E + 63) >> 6;
  int t = blockIdx.x;
  if (t >= tiles) return;
  int cur = 0;
  {  // prologue: stage tile t into buf[0]
    int base = t << 6;
    int ne = min(64, E - base);
    uint2 pk[8];
    if (srow < ne) {
      int d = csr_dst[base + srow], s = csr_src[base + srow];
      const uint2* Ar = (const uint2*)(A + (size_t)d * H + sq * 32);
      const uint2* Br = (const uint2*)(Bm + (size_t)s * H + sq * 32);
#pragma unroll
      for (int i = 0; i < 8; ++i) {
        uint2 va = Ar[i], vb = Br[i];
        pk[i].x = pack2bf(fmaxf(bflo(va.x) + bflo(vb.x), 0.f), fmaxf(bfhi(va.x) + bfhi(vb.x), 0.f));
        pk[i].y = pack2bf(fmaxf(bflo(va.y) + bflo(vb.y), 0.f), fmaxf(bfhi(va.y) + bfhi(vb.y), 0.f));
      }
    } else {
#pragma unroll
      for (int i = 0; i < 8; ++i) pk[i] = {0u, 0u};
    }
#pragma unroll
    for (int i = 0; i < 8; ++i) *(uint2*)&buf[0][srow][sq * 32 + i * 4] = pk[i];
    if (sq == 0) dbuf[0][srow] = (srow < ne) ? csr_dst[base + srow] : -1;
  }
  __syncthreads();

  for (; t < tiles; t += gridDim.x) {
    const int base = t << 6;
    const int ne = min(64, E - base);
    const int nt = t + gridDim.x;
    const bool havenext = nt < tiles;
    // A: prefetch next tile into registers
    uint2 pk[8];
    if (havenext) {
      int nbase = nt << 6;
      int nne = min(64, E - nbase);
      if (srow < nne) {
        int d = csr_dst[nbase + srow], s = csr_src[nbase + srow];
        const uint2* Ar = (const uint2*)(A + (size_t)d * H + sq * 32);
        const uint2* Br = (const uint2*)(Bm + (size_t)s * H + sq * 32);
#pragma unroll
        for (int i = 0; i < 8; ++i) {
          uint2 va = Ar[i], vb = Br[i];
          pk[i].x =
              pack2bf(fmaxf(bflo(va.x) + bflo(vb.x), 0.f), fmaxf(bfhi(va.x) + bfhi(vb.x), 0.f));
          pk[i].y =
              pack2bf(fmaxf(bflo(va.y) + bflo(vb.y), 0.f), fmaxf(bfhi(va.y) + bfhi(vb.y), 0.f));
        }
      } else {
#pragma unroll
        for (int i = 0; i < 8; ++i) pk[i] = {0u, 0u};
      }
    }
    // B: MFMA on current buffer
    bf16x8 af[4];
#pragma unroll
    for (int kk = 0; kk < 4; ++kk)
      af[kk] = *(const bf16x8*)&buf[cur][wave * 16 + jl][kk * 32 + kg * 8];
    f32x4 acc[8];
#pragma unroll
    for (int jt = 0; jt < 8; ++jt) {
      f32x4 c = {0.f, 0.f, 0.f, 0.f};
#pragma unroll
      for (int kk = 0; kk < 4; ++kk) {
        bf16x8 wf = *(const bf16x8*)&W2T[(size_t)(jt * 16 + jl) * H + kk * 32 + kg * 8];
        c = __builtin_amdgcn_mfma_f32_16x16x32_bf16(af[kk], wf, c, 0, 0, 0);
      }
      acc[jt] = c;
    }
    // C: write staged next tile into alternate buffer
    if (havenext) {
      int nbase = nt << 6;
      int nne = min(64, E - nbase);
#pragma unroll
      for (int i = 0; i < 8; ++i) *(uint2*)&buf[cur ^ 1][srow][sq * 32 + i * 4] = pk[i];
      if (sq == 0) dbuf[cur ^ 1][srow] = (srow < nne) ? csr_dst[nbase + srow] : -1;
    }
    // D: wave0 builds slot map for CURRENT tile
    if (wave == 0) {
      int r = lane;
      int d = dbuf[cur][r];
      int dp = (r == 0) ? -1234567 : dbuf[cur][r - 1];
      int start = (r < ne && d != dp) ? 1 : 0;
      int ps = start;
#pragma unroll
      for (int off = 1; off < 64; off <<= 1) {
        int v = __shfl_up(ps, off);
        if (lane >= off) ps += v;
      }
      int slot = ps - 1;
      slotmap[cur][r] = (r < ne) ? slot : 255;
      if (start && slot < 16) {
        slot_dst2[cur][slot] = d;
        int e0 = row_ptr[d], e1 = row_ptr[d + 1];
        slot_comp2[cur][slot] = (e0 >= base && e1 <= base + ne) ? 1 : 0;
      }
      if (r == 63) nslots2[cur] = ps;
    }
    __syncthreads();
    // E: epilogue — register run-merge, then LDS slot atomics (overflow -> global)
    {
      const int r0 = wave * 16 + kg * 4;
      int dd[4], ss[4];
#pragma unroll
      for (int r = 0; r < 4; ++r) {
        dd[r] = dbuf[cur][r0 + r];
        ss[r] = slotmap[cur][r0 + r];
      }
#pragma unroll
      for (int jt = 0; jt < 8; ++jt) {
        const int col = jt * 16 + jl;
        f32x4 c = acc[jt];
        int cd = dd[0], cs = ss[0];
        float cm = c[0];
#pragma unroll
        for (int r = 1; r < 4; ++r) {
          if (dd[r] == cd) {
            cm = fmaxf(cm, c[r]);
          } else {
            if (cd >= 0) {
              if (cs < 16)
                atomicMax(&slots[cs][col], fenc(cm));
              else
                atomicMax(&hec[(size_t)cd * H + col], fenc(cm + b2v[jt]));
            }
            cd = dd[r];
            cs = ss[r];
            cm = c[r];
          }
        }
        if (cd >= 0) {
          if (cs < 16)
            atomicMax(&slots[cs][col], fenc(cm));
          else
            atomicMax(&hec[(size_t)cd * H + col], fenc(cm + b2v[jt]));
        }
      }
    }
    __syncthreads();
    // F: flush slots -> global (plain store if node complete in tile), zero slots
    {
      int ns = min(nslots2[cur], 16);
      int col = tid & 127, sb = tid >> 7;
#pragma unroll
      for (int k = 0; k < 8; ++k) {
        int s = sb + k * 2;
        if (s < ns) {
          unsigned v = slots[s][col];
          slots[s][col] = 0;
          float f = fdec(v) + b2c;
          size_t off = (size_t)slot_dst2[cur][s] * H + col;
          if (slot_comp2[cur][s])
            hec[off] = fenc(fmaxf(f, 0.f));
          else
            atomicMax(&hec[off], fenc(f));
        }
      }
    }
    cur ^= 1;
  }
}

// ---------- decode hec (ordered u32) -> bf16 rows ----------
__global__ void ec_decode(const unsigned* __restrict__ hec, unsigned short* __restrict__ out,
                          size_t half) {
  size_t i = (size_t)blockIdx.x * 256 + threadIdx.x;
  if (i < half) {
    uint2 v = *(const uint2*)&hec[i * 2];
    ((unsigned*)out)[i] = pack2bf(fdec(v.x), fdec(v.y));
  }
}

// ---------- GIN gather: bf16 input, wave per node, 8x unrolled ----------
__global__ __launch_bounds__(256) void gin_gather(const unsigned short* __restrict__ h,
                                                  const int* __restrict__ row_ptr,
                                                  const int* __restrict__ csr_src,
                                                  unsigned short* __restrict__ out, int n) {
  int node = blockIdx.x * 4 + (threadIdx.x >> 6);
  int lane = threadIdx.x & 63;
  if (node >= n) return;
  const unsigned* hu = (const unsigned*)h;
  unsigned v = hu[(size_t)node * 64 + lane];
  float t0 = bflo(v), t1 = bfhi(v);
  int a = row_ptr[node], b = row_ptr[node + 1];
  int e = a;
  for (; e + 8 <= b; e += 8) {
    int sx[8];
#pragma unroll
    for (int i = 0; i < 8; ++i) sx[i] = csr_src[e + i];
    unsigned w[8];
#pragma unroll
    for (int i = 0; i < 8; ++i) w[i] = hu[(size_t)sx[i] * 64 + lane];
#pragma unroll
    for (int i = 0; i < 8; ++i) {
      t0 += bflo(w[i]);
      t1 += bfhi(w[i]);
    }
  }
  for (; e < b; ++e) {
    int s = csr_src[e];
    unsigned w = hu[(size_t)s * 64 + lane];
    t0 += bflo(w);
    t1 += bfhi(w);
  }
  ((unsigned*)out)[(size_t)node * 64 + lane] = pack2bf(t0, t1);
}

// ---------- pooling ----------
__global__ void starts_kernel(const int* __restrict__ batch, int* __restrict__ starts, int n,
                              int G) {
  int i = blockIdx.x * 256 + threadIdx.x;
  if (i >= n) return;
  int b = batch[i];
  int bp = (i == 0) ? -1 : batch[i - 1];
  for (int g = bp + 1; g <= b; ++g) starts[g] = i;
  if (i == n - 1)
    for (int g = b + 1; g <= G; ++g) starts[g] = n;
}
__global__ __launch_bounds__(256) void pool_fused(float* __restrict__ gate,
                                                  const unsigned short* __restrict__ h4,
                                                  const int* __restrict__ starts,
                                                  const float* __restrict__ fcW,
                                                  const float* __restrict__ fcB,
                                                  float* __restrict__ out) {
  __shared__ float red[256];
  __shared__ float pl[128];
  int g = blockIdx.x, t = threadIdx.x;
  int s0 = starts[g], s1 = starts[g + 1];
  float m = -1e30f;
  for (int i = s0 + t; i < s1; i += 256) m = fmaxf(m, gate[i]);
  red[t] = m;
  __syncthreads();
  for (int off = 128; off; off >>= 1) {
    if (t < off) red[t] = fmaxf(red[t], red[t + off]);
    __syncthreads();
  }
  m = red[0];
  __syncthreads();
  float sm = 0.f;
  for (int i = s0 + t; i < s1; i += 256) {
    float ge = __expf(gate[i] - m);
    gate[i] = ge;
    sm += ge;
  }
  red[t] = sm;
  __syncthreads();
  for (int off = 128; off; off >>= 1) {
    if (t < off) red[t] += red[t + off];
    __syncthreads();
  }
  float inv = 1.f / (red[0] + 1e-16f);
  __syncthreads();
  int c = t & 127, half = t >> 7;
  float acc = 0.f;
  for (int i = s0 + half; i < s1; i += 2) acc = fmaf(gate[i], bf2f(h4[(size_t)i * H + c]), acc);
  red[t] = acc;
  __syncthreads();
  if (t < 128) pl[t] = (red[t] + red[t + 128]) * inv;
  __syncthreads();
  if (t < OUTD) {
    float o = fcB[t];
    for (int k = 0; k < 128; ++k) o = fmaf(pl[k], fcW[k * OUTD + t], o);
    red[t] = o;
  }
  __syncthreads();
  if (t == 0) {
    float mm = -1e30f;
    for (int j = 0; j < OUTD; ++j) mm = fmaxf(mm, red[j]);
    float s = 0.f;
    for (int j = 0; j < OUTD; ++j) s += __expf(red[j] - mm);
    float l = logf(s);
    for (int j = 0; j < OUTD; ++j) out[g * OUTD + j] = red[j] - mm - l;
  }
}

extern "C" void kernel_launch(void* const* d_in, const int* in_sizes, int n_in, void* d_out,
                              int out_size, void* d_ws, size_t ws_size, hipStream_t stream) {
  const float* x = (const float*)d_in[0];
  const int* ei = (const int*)d_in[1];
  const int* batch = (const int*)d_in[2];
  const float* gcnW = (const float*)d_in[3];
  const float* gcnB = (const float*)d_in[4];
  const float* gatW = (const float*)d_in[5];
  const float* attS = (const float*)d_in[6];
  const float* attD = (const float*)d_in[7];
  const float* gatB = (const float*)d_in[8];
  const float* ecW1 = (const float*)d_in[9];
  const float* ecB1 = (const float*)d_in[10];
  const float* ecW2 = (const float*)d_in[11];
  const float* ecB2 = (const float*)d_in[12];
  const float* ginW1 = (const float*)d_in[13];
  const float* ginB1 = (const float*)d_in[14];
  const float* ginW2 = (const float*)d_in[15];
  const float* ginB2 = (const float*)d_in[16];
  const float* gtW1 = (const float*)d_in[17];
  const float* gtB1 = (const float*)d_in[18];
  const float* gtW2 = (const float*)d_in[19];
  const float* gtB2 = (const float*)d_in[20];
  const float* fcW = (const float*)d_in[21];
  const float* fcB = (const float*)d_in[22];

  const int N = in_sizes[0] / H;
  const int E = in_sizes[1] / 2;
  const int G = out_size / OUTD;
  const size_t NH = (size_t)N * H;

  auto align16 = [](char* p) { return (char*)(((uintptr_t)p + 15) & ~(uintptr_t)15); };
  char* p = (char*)d_ws;
  unsigned* hec = (unsigned*)p;      p += NH * 4;
  float* dinv = (float*)p;           p += (size_t)N * 4;
  float* asrc = (float*)p;           p += (size_t)4 * N * 4;
  float* adst = (float*)p;           p += (size_t)4 * N * 4;
  float* gate = (float*)p;           p += (size_t)N * 4;
  int* starts = (int*)p;             p += (size_t)(G + 1) * 4;
  int* cnt = (int*)p;                p += (size_t)N * 4;
  int* row_ptr = (int*)p;            p += (size_t)(N + 1) * 4;
  int* cursor = (int*)p;             p += (size_t)N * 4;
  int* csr_src = (int*)p;            p += (size_t)E * 4;
  int* csr_dst = (int*)p;            p += (size_t)E * 4;
  p = align16(p);
  unsigned short* WT = (unsigned short*)p;  p += (size_t)8 * 16384 * 2;
  p = align16(p);
  unsigned short* T0 = (unsigned short*)p;  p += NH * 2;
  p = align16(p);
  unsigned short* T1 = (unsigned short*)p;  p += NH * 2;
  p = align16(p);
  unsigned short* T2 = (unsigned short*)p;  p += NH * 2;

  const unsigned short* gcnT = WT;
  const unsigned short* gatT = WT + 16384;
  const unsigned short* WaT = WT + 2 * 16384;
  const unsigned short* WbT = WT + 3 * 16384;
  const unsigned short* W2T = WT + 4 * 16384;
  const unsigned short* gin1T = WT + 5 * 16384;
  const unsigned short* gin2T = WT + 6 * 16384;
  const unsigned short* gt1T = WT + 7 * 16384;

  const int gN = (N + 255) / 256;
  const int gNH = (int)((NH + 255) / 256);
  const int gE = (E + 255) / 256;
  const int gDense = (N + 63) / 64;
  const int gW4 = (N + 3) / 4;

  // ---- prep + CSR ----
  prep_w<<<(8 * 16384 + 255) / 256, 256, 0, stream>>>(gcnW, gatW, ecW1, ecW2, ginW1, ginW2,
                                                      gtW1, WT);
  zero_int<<<gN, 256, 0, stream>>>(cnt, N);
  csr_count<<<gE, 256, 0, stream>>>(ei, cnt, E);
  scan50k<<<1, 1024, 0, stream>>>(cnt, row_ptr, N);
  copy_int<<<gN, 256, 0, stream>>>(row_ptr, cursor, N);
  csr_fill<<<gE, 256, 0, stream>>>(ei, cursor, csr_src, csr_dst, E);
  dinv_kernel<<<gN, 256, 0, stream>>>(row_ptr, dinv, N);

  // ---- GCN ----
  dense_mfma<0, 0, 0><<<gDense, 256, 0, stream>>>(x, gcnT, nullptr, T0, N);
  gcn_gather<<<gW4, 256, 0, stream>>>(T0, dinv, row_ptr, csr_src, gcnB, T1, N);

  // ---- GAT ----
  dense_mfma<1, 0, 0><<<gDense, 256, 0, stream>>>(T1, gatT, nullptr, T2, N);
  att_pre<<<(N * 4 + 255) / 256, 256, 0, stream>>>(T2, attS, attD, asrc, adst, N);
  gat_gather<<<gW4, 256, 0, stream>>>(T2, asrc, adst, row_ptr, csr_src, gatB, T0, N);

  // ---- EdgeConv ----
  dense_dual<<<gDense, 256, 0, stream>>>(T0, WaT, WbT, ecB1, T1, T2, N);
  fill_u32<<<gNH, 256, 0, stream>>>(hec, 0x80000000u, NH);  // enc(0.0): folds relu + isolated
  edgeconv_tile<<<2048, 256, 0, stream>>>(T1, T2, csr_src, csr_dst, row_ptr, W2T, ecB2, hec, E);
  ec_decode<<<(int)((NH / 2 + 255) / 256), 256, 0, stream>>>(hec, T0, NH / 2);

  // ---- GIN ----
  gin_gather<<<gW4, 256, 0, stream>>>(T0, row_ptr, csr_src, T1, N);
  dense_chain<<<gDense, 256, 0, stream>>>(T1, gin1T, ginB1, gin2T, ginB2, T2, N);  // h4 = T2

  // ---- gating + pooling ----
  dense_gate<<<gDense, 256, 0, stream>>>(T2, gt1T, gtB1, gtW2, gtB2, gate, N);
  starts_kernel<<<gN, 256, 0, stream>>>(batch, starts, N, G);
  pool_fused<<<G, 256, 0, stream>>>(gate, T2, starts, fcW, fcB, (float*)d_out);
}

// Round 9
// 811.332 us; speedup vs baseline: 1.0406x; 1.0406x over previous
//
#include <hip/hip_runtime.h>

#define H 128
#define OUTD 10

typedef short bf16x8 __attribute__((ext_vector_type(8)));
typedef float f32x4 __attribute__((ext_vector_type(4)));

// ---------- bf16 helpers ----------
__device__ __forceinline__ unsigned short f2bf(float x) {
  unsigned u = __float_as_uint(x);
  u += 0x7fffu + ((u >> 16) & 1u);  // RNE
  return (unsigned short)(u >> 16);
}
__device__ __forceinline__ unsigned pack2bf(float a, float b) {
  return (unsigned)f2bf(a) | ((unsigned)f2bf(b) << 16);
}
__device__ __forceinline__ float bf2f(unsigned short u) {
  return __uint_as_float(((unsigned)u) << 16);
}
__device__ __forceinline__ float bflo(unsigned u) { return __uint_as_float(u << 16); }
__device__ __forceinline__ float bfhi(unsigned u) { return __uint_as_float(u & 0xffff0000u); }
__device__ __forceinline__ unsigned addrelu2(unsigned a, unsigned b) {
  return pack2bf(fmaxf(bflo(a) + bflo(b), 0.f), fmaxf(bfhi(a) + bfhi(b), 0.f));
}

// ---------- ordered-float encoding for atomic max ----------
__device__ __forceinline__ unsigned fenc(float x) {
  unsigned u = __float_as_uint(x);
  return (u & 0x80000000u) ? ~u : (u | 0x80000000u);
}
__device__ __forceinline__ float fdec(unsigned u) {
  u = (u & 0x80000000u) ? (u & 0x7fffffffu) : ~u;
  return __uint_as_float(u);
}

// ---------- weight prep: 8 matrices -> bf16 transposed [j][k] ----------
__global__ void prep_w(const float* __restrict__ gcnW, const float* __restrict__ gatW,
                       const float* __restrict__ ecW1, const float* __restrict__ ecW2,
                       const float* __restrict__ ginW1, const float* __restrict__ ginW2,
                       const float* __restrict__ gtW1, unsigned short* __restrict__ WT) {
  int f = blockIdx.x * 256 + threadIdx.x;
  if (f >= 8 * 16384) return;
  int m = f >> 14, idx = f & 16383;
  int j = idx >> 7, k = idx & 127;
  int src = k * 128 + j;
  float v;
  switch (m) {
    case 0: v = gcnW[src]; break;
    case 1: v = gatW[src]; break;
    case 2: v = ecW1[src] - ecW1[16384 + src]; break;  // Wa = top - bot
    case 3: v = ecW1[16384 + src]; break;              // Wb
    case 4: v = ecW2[src]; break;
    case 5: v = ginW1[src]; break;
    case 6: v = ginW2[src]; break;
    default: v = gtW1[src]; break;
  }
  WT[f] = f2bf(v);
}

// ---------- MFMA dense [n,128]@[128,128], W^T bf16 in global (L1), bf16 out ----------
template <int IN_BF, int RELU, int BIAS>
__global__ __launch_bounds__(256) void dense_mfma(const void* __restrict__ Xv,
                                                  const unsigned short* __restrict__ WT,
                                                  const float* __restrict__ bias,
                                                  unsigned short* __restrict__ Y, int n) {
  __shared__ unsigned short tile[64][136];
  const int tid = threadIdx.x, lane = tid & 63, wave = tid >> 6;
  const int jl = lane & 15, kg = lane >> 4;
  const int base = blockIdx.x * 64;
  if (base >= n) return;
  const int nr = min(64, n - base);
  if (IN_BF) {
    const uint4* X4 = (const uint4*)Xv;
#pragma unroll
    for (int it = 0; it < 4; ++it) {
      int f = it * 256 + tid, r = f >> 4, q = f & 15;
      if (r < nr) *(uint4*)&tile[r][q * 8] = X4[(size_t)(base + r) * 16 + q];
    }
  } else {
    const float* X = (const float*)Xv;
#pragma unroll
    for (int it = 0; it < 16; ++it) {
      int f = it * 256 + tid, r = f >> 6, kp = f & 63;
      if (r < nr) {
        float2 v = *(const float2*)&X[(size_t)(base + r) * H + 2 * kp];
        *(unsigned*)&tile[r][2 * kp] = pack2bf(v.x, v.y);
      }
    }
  }
  __syncthreads();
  bf16x8 afrag[4];
#pragma unroll
  for (int kk = 0; kk < 4; ++kk)
    afrag[kk] = *(const bf16x8*)&tile[wave * 16 + jl][kk * 32 + kg * 8];
  f32x4 acc[8];
#pragma unroll
  for (int jt = 0; jt < 8; ++jt) {
    f32x4 c = {0.f, 0.f, 0.f, 0.f};
#pragma unroll
    for (int kk = 0; kk < 4; ++kk) {
      bf16x8 bf = *(const bf16x8*)&WT[(size_t)(jt * 16 + jl) * H + kk * 32 + kg * 8];
      c = __builtin_amdgcn_mfma_f32_16x16x32_bf16(afrag[kk], bf, c, 0, 0, 0);
    }
    if (BIAS) {
      float bb = bias[jt * 16 + jl];
#pragma unroll
      for (int r = 0; r < 4; ++r) c[r] += bb;
    }
    if (RELU) {
#pragma unroll
      for (int r = 0; r < 4; ++r) c[r] = fmaxf(c[r], 0.f);
    }
    acc[jt] = c;
  }
  __syncthreads();
#pragma unroll
  for (int jt = 0; jt < 8; ++jt)
#pragma unroll
    for (int r = 0; r < 4; ++r) tile[wave * 16 + kg * 4 + r][jt * 16 + jl] = f2bf(acc[jt][r]);
  __syncthreads();
#pragma unroll
  for (int it = 0; it < 4; ++it) {
    int f = it * 256 + tid, r = f >> 4, q = f & 15;
    if (r < nr) *(uint4*)&Y[(size_t)(base + r) * H + q * 8] = *(const uint4*)&tile[r][q * 8];
  }
}

// ---------- dual dense: Y1 = X@W1, Y2 = X@W2 + b2 (shared X staging) ----------
__global__ __launch_bounds__(256) void dense_dual(const unsigned short* __restrict__ X,
                                                  const unsigned short* __restrict__ WT1,
                                                  const unsigned short* __restrict__ WT2,
                                                  const float* __restrict__ bias2,
                                                  unsigned short* __restrict__ Y1,
                                                  unsigned short* __restrict__ Y2, int n) {
  __shared__ unsigned short tile[64][136];
  const int tid = threadIdx.x, lane = tid & 63, wave = tid >> 6;
  const int jl = lane & 15, kg = lane >> 4;
  const int base = blockIdx.x * 64;
  if (base >= n) return;
  const int nr = min(64, n - base);
  const uint4* X4 = (const uint4*)X;
#pragma unroll
  for (int it = 0; it < 4; ++it) {
    int f = it * 256 + tid, r = f >> 4, q = f & 15;
    if (r < nr) *(uint4*)&tile[r][q * 8] = X4[(size_t)(base + r) * 16 + q];
  }
  __syncthreads();
  bf16x8 afrag[4];
#pragma unroll
  for (int kk = 0; kk < 4; ++kk)
    afrag[kk] = *(const bf16x8*)&tile[wave * 16 + jl][kk * 32 + kg * 8];
  f32x4 acc[8];
#pragma unroll
  for (int jt = 0; jt < 8; ++jt) {
    f32x4 c = {0.f, 0.f, 0.f, 0.f};
#pragma unroll
    for (int kk = 0; kk < 4; ++kk) {
      bf16x8 bf = *(const bf16x8*)&WT1[(size_t)(jt * 16 + jl) * H + kk * 32 + kg * 8];
      c = __builtin_amdgcn_mfma_f32_16x16x32_bf16(afrag[kk], bf, c, 0, 0, 0);
    }
    acc[jt] = c;
  }
  __syncthreads();
#pragma unroll
  for (int jt = 0; jt < 8; ++jt)
#pragma unroll
    for (int r = 0; r < 4; ++r) tile[wave * 16 + kg * 4 + r][jt * 16 + jl] = f2bf(acc[jt][r]);
  __syncthreads();
#pragma unroll
  for (int it = 0; it < 4; ++it) {
    int f = it * 256 + tid, r = f >> 4, q = f & 15;
    if (r < nr) *(uint4*)&Y1[(size_t)(base + r) * H + q * 8] = *(const uint4*)&tile[r][q * 8];
  }
  __syncthreads();
#pragma unroll
  for (int jt = 0; jt < 8; ++jt) {
    f32x4 c = {0.f, 0.f, 0.f, 0.f};
#pragma unroll
    for (int kk = 0; kk < 4; ++kk) {
      bf16x8 bf = *(const bf16x8*)&WT2[(size_t)(jt * 16 + jl) * H + kk * 32 + kg * 8];
      c = __builtin_amdgcn_mfma_f32_16x16x32_bf16(afrag[kk], bf, c, 0, 0, 0);
    }
    float bb = bias2[jt * 16 + jl];
#pragma unroll
    for (int r = 0; r < 4; ++r) c[r] += bb;
    acc[jt] = c;
  }
  __syncthreads();
#pragma unroll
  for (int jt = 0; jt < 8; ++jt)
#pragma unroll
    for (int r = 0; r < 4; ++r) tile[wave * 16 + kg * 4 + r][jt * 16 + jl] = f2bf(acc[jt][r]);
  __syncthreads();
#pragma unroll
  for (int it = 0; it < 4; ++it) {
    int f = it * 256 + tid, r = f >> 4, q = f & 15;
    if (r < nr) *(uint4*)&Y2[(size_t)(base + r) * H + q * 8] = *(const uint4*)&tile[r][q * 8];
  }
}

// ---------- chained dense (GIN): Y = relu(relu(X@W1+b1)@W2+b2) ----------
__global__ __launch_bounds__(256) void dense_chain(const unsigned short* __restrict__ X,
                                                   const unsigned short* __restrict__ WT1,
                                                   const float* __restrict__ b1,
                                                   const unsigned short* __restrict__ WT2,
                                                   const float* __restrict__ b2,
                                                   unsigned short* __restrict__ Y, int n) {
  __shared__ unsigned short tile[64][136];
  const int tid = threadIdx.x, lane = tid & 63, wave = tid >> 6;
  const int jl = lane & 15, kg = lane >> 4;
  const int base = blockIdx.x * 64;
  if (base >= n) return;
  const int nr = min(64, n - base);
  const uint4* X4 = (const uint4*)X;
#pragma unroll
  for (int it = 0; it < 4; ++it) {
    int f = it * 256 + tid, r = f >> 4, q = f & 15;
    if (r < nr) *(uint4*)&tile[r][q * 8] = X4[(size_t)(base + r) * 16 + q];
  }
  __syncthreads();
  bf16x8 af[4];
#pragma unroll
  for (int kk = 0; kk < 4; ++kk) af[kk] = *(const bf16x8*)&tile[wave * 16 + jl][kk * 32 + kg * 8];
  f32x4 acc[8];
#pragma unroll
  for (int jt = 0; jt < 8; ++jt) {
    f32x4 c = {0.f, 0.f, 0.f, 0.f};
#pragma unroll
    for (int kk = 0; kk < 4; ++kk) {
      bf16x8 bf = *(const bf16x8*)&WT1[(size_t)(jt * 16 + jl) * H + kk * 32 + kg * 8];
      c = __builtin_amdgcn_mfma_f32_16x16x32_bf16(af[kk], bf, c, 0, 0, 0);
    }
    float bb = b1[jt * 16 + jl];
#pragma unroll
    for (int r = 0; r < 4; ++r) c[r] = fmaxf(c[r] + bb, 0.f);
    acc[jt] = c;
  }
  __syncthreads();
#pragma unroll
  for (int jt = 0; jt < 8; ++jt)
#pragma unroll
    for (int r = 0; r < 4; ++r) tile[wave * 16 + kg * 4 + r][jt * 16 + jl] = f2bf(acc[jt][r]);
  __syncthreads();
#pragma unroll
  for (int kk = 0; kk < 4; ++kk) af[kk] = *(const bf16x8*)&tile[wave * 16 + jl][kk * 32 + kg * 8];
#pragma unroll
  for (int jt = 0; jt < 8; ++jt) {
    f32x4 c = {0.f, 0.f, 0.f, 0.f};
#pragma unroll
    for (int kk = 0; kk < 4; ++kk) {
      bf16x8 bf = *(const bf16x8*)&WT2[(size_t)(jt * 16 + jl) * H + kk * 32 + kg * 8];
      c = __builtin_amdgcn_mfma_f32_16x16x32_bf16(af[kk], bf, c, 0, 0, 0);
    }
    float bb = b2[jt * 16 + jl];
#pragma unroll
    for (int r = 0; r < 4; ++r) c[r] = fmaxf(c[r] + bb, 0.f);
    acc[jt] = c;
  }
  __syncthreads();
#pragma unroll
  for (int jt = 0; jt < 8; ++jt)
#pragma unroll
    for (int r = 0; r < 4; ++r) tile[wave * 16 + kg * 4 + r][jt * 16 + jl] = f2bf(acc[jt][r]);
  __syncthreads();
#pragma unroll
  for (int it = 0; it < 4; ++it) {
    int f = it * 256 + tid, r = f >> 4, q = f & 15;
    if (r < nr) *(uint4*)&Y[(size_t)(base + r) * H + q * 8] = *(const uint4*)&tile[r][q * 8];
  }
}

// ---------- gate dense: gate = relu(X@W1+b1) . w2 + b2 ----------
__global__ __launch_bounds__(256) void dense_gate(const unsigned short* __restrict__ X,
                                                  const unsigned short* __restrict__ WT,
                                                  const float* __restrict__ b1,
                                                  const float* __restrict__ w2,
                                                  const float* __restrict__ b2,
                                                  float* __restrict__ gate, int n) {
  __shared__ unsigned short tile[64][136];
  const int tid = threadIdx.x, lane = tid & 63, wave = tid >> 6;
  const int jl = lane & 15, kg = lane >> 4;
  const int base = blockIdx.x * 64;
  if (base >= n) return;
  const int nr = min(64, n - base);
  const uint4* X4 = (const uint4*)X;
#pragma unroll
  for (int it = 0; it < 4; ++it) {
    int f = it * 256 + tid, r = f >> 4, q = f & 15;
    if (r < nr) *(uint4*)&tile[r][q * 8] = X4[(size_t)(base + r) * 16 + q];
  }
  __syncthreads();
  bf16x8 af[4];
#pragma unroll
  for (int kk = 0; kk < 4; ++kk) af[kk] = *(const bf16x8*)&tile[wave * 16 + jl][kk * 32 + kg * 8];
  float p0 = 0.f, p1 = 0.f, p2 = 0.f, p3 = 0.f;
#pragma unroll
  for (int jt = 0; jt < 8; ++jt) {
    f32x4 c = {0.f, 0.f, 0.f, 0.f};
#pragma unroll
    for (int kk = 0; kk < 4; ++kk) {
      bf16x8 bf = *(const bf16x8*)&WT[(size_t)(jt * 16 + jl) * H + kk * 32 + kg * 8];
      c = __builtin_amdgcn_mfma_f32_16x16x32_bf16(af[kk], bf, c, 0, 0, 0);
    }
    float bb = b1[jt * 16 + jl];
    float wv = w2[jt * 16 + jl];
    p0 = fmaf(fmaxf(c[0] + bb, 0.f), wv, p0);
    p1 = fmaf(fmaxf(c[1] + bb, 0.f), wv, p1);
    p2 = fmaf(fmaxf(c[2] + bb, 0.f), wv, p2);
    p3 = fmaf(fmaxf(c[3] + bb, 0.f), wv, p3);
  }
#pragma unroll
  for (int off = 1; off <= 8; off <<= 1) {
    p0 += __shfl_xor(p0, off);
    p1 += __shfl_xor(p1, off);
    p2 += __shfl_xor(p2, off);
    p3 += __shfl_xor(p3, off);
  }
  if (jl == 0) {
    float bb2 = b2[0];
    int row = wave * 16 + kg * 4;
    if (row + 0 < nr) gate[base + row + 0] = p0 + bb2;
    if (row + 1 < nr) gate[base + row + 1] = p1 + bb2;
    if (row + 2 < nr) gate[base + row + 2] = p2 + bb2;
    if (row + 3 < nr) gate[base + row + 3] = p3 + bb2;
  }
}

// ---------- CSR build ----------
__global__ void zero_int(int* p, int n) {
  int i = blockIdx.x * 256 + threadIdx.x;
  if (i < n) p[i] = 0;
}
__global__ void csr_count(const int* __restrict__ ei, int* __restrict__ cnt, int E) {
  int e = blockIdx.x * 256 + threadIdx.x;
  if (e < E) atomicAdd(&cnt[ei[(size_t)E + e]], 1);
}
__global__ __launch_bounds__(1024) void scan50k(const int* __restrict__ cnt,
                                                int* __restrict__ row_ptr, int n) {
  __shared__ int ls[1024];
  int t = threadIdx.x;
  int chunk = (n + 1023) >> 10;
  int a = t * chunk;
  if (a > n) a = n;
  int b = a + chunk;
  if (b > n) b = n;
  int s = 0;
  for (int i = a; i < b; ++i) s += cnt[i];
  ls[t] = s;
  __syncthreads();
  for (int off = 1; off < 1024; off <<= 1) {
    int v = (t >= off) ? ls[t - off] : 0;
    __syncthreads();
    ls[t] += v;
    __syncthreads();
  }
  int run = (t > 0) ? ls[t - 1] : 0;
  for (int i = a; i < b; ++i) {
    row_ptr[i] = run;
    run += cnt[i];
  }
  if (t == 1023) row_ptr[n] = ls[1023];
}
__global__ void copy_int(const int* __restrict__ a, int* __restrict__ b, int n) {
  int i = blockIdx.x * 256 + threadIdx.x;
  if (i < n) b[i] = a[i];
}
__global__ void csr_fill(const int* __restrict__ ei, int* __restrict__ cursor,
                         int* __restrict__ csr_src, int* __restrict__ csr_dst, int E) {
  int e = blockIdx.x * 256 + threadIdx.x;
  if (e >= E) return;
  int s = ei[e], d = ei[(size_t)E + e];
  int p = atomicAdd(&cursor[d], 1);
  csr_src[p] = s;
  csr_dst[p] = d;
}
__global__ void dinv_kernel(const int* __restrict__ row_ptr, float* __restrict__ dinv, int n) {
  int i = blockIdx.x * 256 + threadIdx.x;
  if (i < n) dinv[i] = rsqrtf((float)(1 + row_ptr[i + 1] - row_ptr[i]));
}
__global__ void fill_u32(unsigned* p, unsigned v, size_t n) {
  size_t i = (size_t)blockIdx.x * 256 + threadIdx.x;
  if (i < n) p[i] = v;
}

// ---------- GCN gather: wave per node, 8x unrolled ----------
__global__ __launch_bounds__(256) void gcn_gather(const unsigned short* __restrict__ h,
                                                  const float* __restrict__ dinv,
                                                  const int* __restrict__ row_ptr,
                                                  const int* __restrict__ csr_src,
                                                  const float* __restrict__ bias,
                                                  unsigned short* __restrict__ out, int n) {
  int node = blockIdx.x * 4 + (threadIdx.x >> 6);
  int lane = threadIdx.x & 63;
  if (node >= n) return;
  const unsigned* hu = (const unsigned*)h;
  float di = dinv[node];
  unsigned v = hu[(size_t)node * 64 + lane];
  float t0 = bflo(v) * di, t1 = bfhi(v) * di;
  int a = row_ptr[node], b = row_ptr[node + 1];
  int e = a;
  for (; e + 8 <= b; e += 8) {
    int sx[8];
#pragma unroll
    for (int i = 0; i < 8; ++i) sx[i] = csr_src[e + i];
    unsigned w[8];
    float dd[8];
#pragma unroll
    for (int i = 0; i < 8; ++i) w[i] = hu[(size_t)sx[i] * 64 + lane];
#pragma unroll
    for (int i = 0; i < 8; ++i) dd[i] = dinv[sx[i]];
#pragma unroll
    for (int i = 0; i < 8; ++i) {
      t0 = fmaf(bflo(w[i]), dd[i], t0);
      t1 = fmaf(bfhi(w[i]), dd[i], t1);
    }
  }
  for (; e < b; ++e) {
    int s = csr_src[e];
    float ds = dinv[s];
    unsigned w = hu[(size_t)s * 64 + lane];
    t0 = fmaf(bflo(w), ds, t0);
    t1 = fmaf(bfhi(w), ds, t1);
  }
  float y0 = fmaxf(fmaf(t0, di, bias[lane * 2]), 0.f);
  float y1 = fmaxf(fmaf(t1, di, bias[lane * 2 + 1]), 0.f);
  ((unsigned*)out)[(size_t)node * 64 + lane] = pack2bf(y0, y1);
}

__global__ void att_pre(const unsigned short* __restrict__ g, const float* __restrict__ attS,
                        const float* __restrict__ attD, float* __restrict__ asrc,
                        float* __restrict__ adst, int n) {
  int t = blockIdx.x * 256 + threadIdx.x;
  if (t >= n * 4) return;
  int i = t >> 2, hd = t & 3;
  const unsigned* gr = (const unsigned*)(g + (size_t)i * H + hd * 32);
  float s1 = 0.f, s2 = 0.f;
#pragma unroll
  for (int p = 0; p < 16; ++p) {
    unsigned u = gr[p];
    float a = bflo(u), b = bfhi(u);
    s1 = fmaf(a, attS[hd * 32 + 2 * p], fmaf(b, attS[hd * 32 + 2 * p + 1], s1));
    s2 = fmaf(a, attD[hd * 32 + 2 * p], fmaf(b, attD[hd * 32 + 2 * p + 1], s2));
  }
  asrc[t] = s1;
  adst[t] = s2;
}

__device__ __forceinline__ float lrelu_exp(float v) {
  v = v > 0.f ? v : 0.2f * v;
  return __expf(v);
}

// ---------- GAT gather: wave per node, 8x unrolled ----------
__global__ __launch_bounds__(256) void gat_gather(const unsigned short* __restrict__ g,
                                                  const float* __restrict__ asrc,
                                                  const float* __restrict__ adst,
                                                  const int* __restrict__ row_ptr,
                                                  const int* __restrict__ csr_src,
                                                  const float* __restrict__ bias,
                                                  unsigned short* __restrict__ out, int n) {
  int node = blockIdx.x * 4 + (threadIdx.x >> 6);
  int lane = threadIdx.x & 63;
  if (node >= n) return;
  const int hd = lane >> 4;
  const unsigned* gu = (const unsigned*)g;
  float adc = adst[node * 4 + hd];
  float w = lrelu_exp(asrc[node * 4 + hd] + adc);
  unsigned u = gu[(size_t)node * 64 + lane];
  float acc0 = w * bflo(u), acc1 = w * bfhi(u), wsum = w;
  int a = row_ptr[node], b = row_ptr[node + 1];
  int e = a;
  for (; e + 8 <= b; e += 8) {
    int sx[8];
#pragma unroll
    for (int i = 0; i < 8; ++i) sx[i] = csr_src[e + i];
    unsigned uu[8];
#pragma unroll
    for (int i = 0; i < 8; ++i) uu[i] = gu[(size_t)sx[i] * 64 + lane];
    float ww[8];
#pragma unroll
    for (int i = 0; i < 8; ++i) ww[i] = lrelu_exp(asrc[sx[i] * 4 + hd] + adc);
#pragma unroll
    for (int i = 0; i < 8; ++i) {
      acc0 = fmaf(ww[i], bflo(uu[i]), acc0);
      acc1 = fmaf(ww[i], bfhi(uu[i]), acc1);
      wsum += ww[i];
    }
  }
  for (; e < b; ++e) {
    int s = csr_src[e];
    unsigned us = gu[(size_t)s * 64 + lane];
    float we = lrelu_exp(asrc[s * 4 + hd] + adc);
    acc0 = fmaf(we, bflo(us), acc0);
    acc1 = fmaf(we, bfhi(us), acc1);
    wsum += we;
  }
  float inv = 1.f / (wsum + 1e-16f);
  float r0 = acc0 * inv + bias[2 * lane];
  float r1 = acc1 * inv + bias[2 * lane + 1];
  r0 = r0 > 0.f ? r0 : expm1f(r0);
  r1 = r1 > 0.f ? r1 : expm1f(r1);
  ((unsigned*)out)[(size_t)node * 64 + lane] = pack2bf(r0, r1);
}

// ---------- EC1: edge message build (pure gather, sequential write) ----------
__global__ __launch_bounds__(256) void ec_msg(const unsigned short* __restrict__ A,
                                              const unsigned short* __restrict__ Bm,
                                              const int* __restrict__ csr_src,
                                              const int* __restrict__ csr_dst,
                                              unsigned short* __restrict__ msg, int E) {
  const int tid = threadIdx.x;
  const int qid = tid >> 4;  // 16 edges per block pass
  const int ql = tid & 15;   // 16 lanes per edge, uint4 (16B) each
  for (int e0 = blockIdx.x * 16; e0 < E; e0 += gridDim.x * 16) {
    int e = e0 + qid;
    if (e < E) {
      int d = csr_dst[e], s = csr_src[e];
      uint4 va = *(const uint4*)(A + (size_t)d * H + ql * 8);
      uint4 vb = *(const uint4*)(Bm + (size_t)s * H + ql * 8);
      uint4 o;
      o.x = addrelu2(va.x, vb.x);
      o.y = addrelu2(va.y, vb.y);
      o.z = addrelu2(va.z, vb.z);
      o.w = addrelu2(va.w, vb.w);
      *(uint4*)(msg + (size_t)e * H + ql * 8) = o;
    }
  }
}

// ---------- EC2: streaming tile MFMA + register segmented max (sequential staging) ----------
__global__ __launch_bounds__(256) void edgeconv_stream(const unsigned short* __restrict__ msg,
                                                       const int* __restrict__ csr_dst,
                                                       const unsigned short* __restrict__ W2T,
                                                       const float* __restrict__ b2,
                                                       unsigned* __restrict__ hec, int E) {
  __shared__ unsigned short buf[2][64][136];
  __shared__ int dbuf[2][64];
  const int tid = threadIdx.x, lane = tid & 63, wave = tid >> 6;
  const int jl = lane & 15, kg = lane >> 4;
  const int srow = tid >> 2, sq = tid & 3;
  float b2v[8];
#pragma unroll
  for (int jt = 0; jt < 8; ++jt) b2v[jt] = b2[jt * 16 + jl];

  const int tiles = (E + 63) >> 6;
  int t = blockIdx.x;
  if (t >= tiles) return;
  int cur = 0;
  {  // prologue
    int base = t << 6;
    int ne = min(64, E - base);
    uint4 pk[4];
    if (srow < ne) {
#pragma unroll
      for (int i = 0; i < 4; ++i)
        pk[i] = *(const uint4*)&msg[(size_t)(base + srow) * H + sq * 32 + i * 8];
    } else {
#pragma unroll
      for (int i = 0; i < 4; ++i) pk[i] = {0u, 0u, 0u, 0u};
    }
#pragma unroll
    for (int i = 0; i < 4; ++i) *(uint4*)&buf[0][srow][sq * 32 + i * 8] = pk[i];
    if (sq == 0) dbuf[0][srow] = (srow < ne) ? csr_dst[base + srow] : -1;
  }
  __syncthreads();

  for (; t < tiles; t += gridDim.x) {
    const int nt = t + gridDim.x;
    const bool havenext = nt < tiles;
    // prefetch next tile (sequential loads)
    uint4 pk[4];
    int nne = 0;
    if (havenext) {
      int nbase = nt << 6;
      nne = min(64, E - nbase);
      if (srow < nne) {
#pragma unroll
        for (int i = 0; i < 4; ++i)
          pk[i] = *(const uint4*)&msg[(size_t)(nbase + srow) * H + sq * 32 + i * 8];
      } else {
#pragma unroll
        for (int i = 0; i < 4; ++i) pk[i] = {0u, 0u, 0u, 0u};
      }
    }
    // MFMA
    bf16x8 af[4];
#pragma unroll
    for (int kk = 0; kk < 4; ++kk)
      af[kk] = *(const bf16x8*)&buf[cur][wave * 16 + jl][kk * 32 + kg * 8];
    const int r0 = wave * 16 + kg * 4;
    const int d0 = dbuf[cur][r0 + 0], d1 = dbuf[cur][r0 + 1];
    const int d2 = dbuf[cur][r0 + 2], d3 = dbuf[cur][r0 + 3];
#pragma unroll
    for (int jt = 0; jt < 8; ++jt) {
      f32x4 c = {0.f, 0.f, 0.f, 0.f};
#pragma unroll
      for (int kk = 0; kk < 4; ++kk) {
        bf16x8 wf = *(const bf16x8*)&W2T[(size_t)(jt * 16 + jl) * H + kk * 32 + kg * 8];
        c = __builtin_amdgcn_mfma_f32_16x16x32_bf16(af[kk], wf, c, 0, 0, 0);
      }
      // register segmented max + atomic emit (fire-and-forget)
      const int col = jt * 16 + jl;
      int cd = d0;
      float m = c[0];
      if (d1 != cd) {
        if (cd >= 0) atomicMax(&hec[(size_t)cd * H + col], fenc(m + b2v[jt]));
        cd = d1;
        m = c[1];
      } else
        m = fmaxf(m, c[1]);
      if (d2 != cd) {
        if (cd >= 0) atomicMax(&hec[(size_t)cd * H + col], fenc(m + b2v[jt]));
        cd = d2;
        m = c[2];
      } else
        m = fmaxf(m, c[2]);
      if (d3 != cd) {
        if (cd >= 0) atomicMax(&hec[(size_t)cd * H + col], fenc(m + b2v[jt]));
        cd = d3;
        m = c[3];
      } else
        m = fmaxf(m, c[3]);
      if (cd >= 0) atomicMax(&hec[(size_t)cd * H + col], fenc(m + b2v[jt]));
    }
    // write staged next tile
    if (havenext) {
      int nbase = nt << 6;
#pragma unroll
      for (int i = 0; i < 4; ++i) *(uint4*)&buf[cur ^ 1][srow][sq * 32 + i * 8] = pk[i];
      if (sq == 0) dbuf[cur ^ 1][srow] = (srow < nne) ? csr_dst[nbase + srow] : -1;
    }
    __syncthreads();
    cur ^= 1;
  }
}

// ---------- fused fallback (R6 structure): pipelined gather-tile MFMA ----------
__global__ __launch_bounds__(256) void edgeconv_tile(const unsigned short* __restrict__ A,
                                                     const unsigned short* __restrict__ Bm,
                                                     const int* __restrict__ csr_src,
                                                     const int* __restrict__ csr_dst,
                                                     const unsigned short* __restrict__ W2T,
                                                     const float* __restrict__ b2,
                                                     unsigned* __restrict__ hec, int E) {
  __shared__ unsigned short buf[2][64][136];
  __shared__ int dbuf[2][64];
  const int tid = threadIdx.x, lane = tid & 63, wave = tid >> 6;
  const int jl = lane & 15, kg = lane >> 4;
  const int srow = tid >> 2, sq = tid & 3;
  float b2v[8];
#pragma unroll
  for (int jt = 0; jt < 8; ++jt) b2v[jt] = b2[jt * 16 + jl];

  const int tiles = (E + 63) >> 6;
  int t = blockIdx.x;
  if (t >= tiles) return;
  int cur = 0;
  {
    int base = t << 6;
    int ne = min(64, E - base);
    uint2 pk[8];
    if (srow < ne) {
      int d = csr_dst[base + srow], s = csr_src[base + srow];
      const uint2* Ar = (const uint2*)(A + (size_t)d * H + sq * 32);
      const uint2* Br = (const uint2*)(Bm + (size_t)s * H + sq * 32);
#pragma unroll
      for (int i = 0; i < 8; ++i) {
        uint2 va = Ar[i], vb = Br[i];
        pk[i].x = addrelu2(va.x, vb.x);
        pk[i].y = addrelu2(va.y, vb.y);
      }
    } else {
#pragma unroll
      for (int i = 0; i < 8; ++i) pk[i] = {0u, 0u};
    }
#pragma unroll
    for (int i = 0; i < 8; ++i) *(uint2*)&buf[0][srow][sq * 32 + i * 4] = pk[i];
    if (sq == 0) dbuf[0][srow] = (srow < ne) ? csr_dst[base + srow] : -1;
  }
  __syncthreads();

  for (; t < tiles; t += gridDim.x) {
    const int nt = t + gridDim.x;
    const bool havenext = nt < tiles;
    uint2 pk[8];
    if (havenext) {
      int base = nt << 6;
      int ne = min(64, E - base);
      if (srow < ne) {
        int d = csr_dst[base + srow], s = csr_src[base + srow];
        const uint2* Ar = (const uint2*)(A + (size_t)d * H + sq * 32);
        const uint2* Br = (const uint2*)(Bm + (size_t)s * H + sq * 32);
#pragma unroll
        for (int i = 0; i < 8; ++i) {
          uint2 va = Ar[i], vb = Br[i];
          pk[i].x = addrelu2(va.x, vb.x);
          pk[i].y = addrelu2(va.y, vb.y);
        }
      } else {
#pragma unroll
        for (int i = 0; i < 8; ++i) pk[i] = {0u, 0u};
      }
    }
    bf16x8 af[4];
#pragma unroll
    for (int kk = 0; kk < 4; ++kk)
      af[kk] = *(const bf16x8*)&buf[cur][wave * 16 + jl][kk * 32 + kg * 8];
    const int r0 = wave * 16 + kg * 4;
    const int d0 = dbuf[cur][r0 + 0], d1 = dbuf[cur][r0 + 1];
    const int d2 = dbuf[cur][r0 + 2], d3 = dbuf[cur][r0 + 3];
#pragma unroll
    for (int jt = 0; jt < 8; ++jt) {
      f32x4 c = {0.f, 0.f, 0.f, 0.f};
#pragma unroll
      for (int kk = 0; kk < 4; ++kk) {
        bf16x8 wf = *(const bf16x8*)&W2T[(size_t)(jt * 16 + jl) * H + kk * 32 + kg * 8];
        c = __builtin_amdgcn_mfma_f32_16x16x32_bf16(af[kk], wf, c, 0, 0, 0);
      }
      const int col = jt * 16 + jl;
      int cd = d0;
      float m = c[0];
      if (d1 != cd) {
        if (cd >= 0) atomicMax(&hec[(size_t)cd * H + col], fenc(m + b2v[jt]));
        cd = d1;
        m = c[1];
      } else
        m = fmaxf(m, c[1]);
      if (d2 != cd) {
        if (cd >= 0) atomicMax(&hec[(size_t)cd * H + col], fenc(m + b2v[jt]));
        cd = d2;
        m = c[2];
      } else
        m = fmaxf(m, c[2]);
      if (d3 != cd) {
        if (cd >= 0) atomicMax(&hec[(size_t)cd * H + col], fenc(m + b2v[jt]));
        cd = d3;
        m = c[3];
      } else
        m = fmaxf(m, c[3]);
      if (cd >= 0) atomicMax(&hec[(size_t)cd * H + col], fenc(m + b2v[jt]));
    }
    if (havenext) {
      int base = nt << 6;
      int ne = min(64, E - base);
#pragma unroll
      for (int i = 0; i < 8; ++i) *(uint2*)&buf[cur ^ 1][srow][sq * 32 + i * 4] = pk[i];
      if (sq == 0) dbuf[cur ^ 1][srow] = (srow < ne) ? csr_dst[base + srow] : -1;
    }
    __syncthreads();
    cur ^= 1;
  }
}

// ---------- decode hec (ordered u32) -> bf16 rows ----------
__global__ void ec_decode(const unsigned* __restrict__ hec, unsigned short* __restrict__ out,
                          size_t half) {
  size_t i = (size_t)blockIdx.x * 256 + threadIdx.x;
  if (i < half) {
    uint2 v = *(const uint2*)&hec[i * 2];
    ((unsigned*)out)[i] = pack2bf(fdec(v.x), fdec(v.y));
  }
}

// ---------- GIN gather: bf16 input, wave per node, 8x unrolled ----------
__global__ __launch_bounds__(256) void gin_gather(const unsigned short* __restrict__ h,
                                                  const int* __restrict__ row_ptr,
                                                  const int* __restrict__ csr_src,
                                                  unsigned short* __restrict__ out, int n) {
  int node = blockIdx.x * 4 + (threadIdx.x >> 6);
  int lane = threadIdx.x & 63;
  if (node >= n) return;
  const unsigned* hu = (const unsigned*)h;
  unsigned v = hu[(size_t)node * 64 + lane];
  float t0 = bflo(v), t1 = bfhi(v);
  int a = row_ptr[node], b = row_ptr[node + 1];
  int e = a;
  for (; e + 8 <= b; e += 8) {
    int sx[8];
#pragma unroll
    for (int i = 0; i < 8; ++i) sx[i] = csr_src[e + i];
    unsigned w[8];
#pragma unroll
    for (int i = 0; i < 8; ++i) w[i] = hu[(size_t)sx[i] * 64 + lane];
#pragma unroll
    for (int i = 0; i < 8; ++i) {
      t0 += bflo(w[i]);
      t1 += bfhi(w[i]);
    }
  }
  for (; e < b; ++e) {
    int s = csr_src[e];
    unsigned w = hu[(size_t)s * 64 + lane];
    t0 += bflo(w);
    t1 += bfhi(w);
  }
  ((unsigned*)out)[(size_t)node * 64 + lane] = pack2bf(t0, t1);
}

// ---------- pooling ----------
__global__ void starts_kernel(const int* __restrict__ batch, int* __restrict__ starts, int n,
                              int G) {
  int i = blockIdx.x * 256 + threadIdx.x;
  if (i >= n) return;
  int b = batch[i];
  int bp = (i == 0) ? -1 : batch[i - 1];
  for (int g = bp + 1; g <= b; ++g) starts[g] = i;
  if (i == n - 1)
    for (int g = b + 1; g <= G; ++g) starts[g] = n;
}
__global__ __launch_bounds__(256) void pool_fused(float* __restrict__ gate,
                                                  const unsigned short* __restrict__ h4,
                                                  const int* __restrict__ starts,
                                                  const float* __restrict__ fcW,
                                                  const float* __restrict__ fcB,
                                                  float* __restrict__ out) {
  __shared__ float red[256];
  __shared__ float pl[128];
  int g = blockIdx.x, t = threadIdx.x;
  int s0 = starts[g], s1 = starts[g + 1];
  float m = -1e30f;
  for (int i = s0 + t; i < s1; i += 256) m = fmaxf(m, gate[i]);
  red[t] = m;
  __syncthreads();
  for (int off = 128; off; off >>= 1) {
    if (t < off) red[t] = fmaxf(red[t], red[t + off]);
    __syncthreads();
  }
  m = red[0];
  __syncthreads();
  float sm = 0.f;
  for (int i = s0 + t; i < s1; i += 256) {
    float ge = __expf(gate[i] - m);
    gate[i] = ge;
    sm += ge;
  }
  red[t] = sm;
  __syncthreads();
  for (int off = 128; off; off >>= 1) {
    if (t < off) red[t] += red[t + off];
    __syncthreads();
  }
  float inv = 1.f / (red[0] + 1e-16f);
  __syncthreads();
  int c = t & 127, half = t >> 7;
  float acc = 0.f;
  for (int i = s0 + half; i < s1; i += 2) acc = fmaf(gate[i], bf2f(h4[(size_t)i * H + c]), acc);
  red[t] = acc;
  __syncthreads();
  if (t < 128) pl[t] = (red[t] + red[t + 128]) * inv;
  __syncthreads();
  if (t < OUTD) {
    float o = fcB[t];
    for (int k = 0; k < 128; ++k) o = fmaf(pl[k], fcW[k * OUTD + t], o);
    red[t] = o;
  }
  __syncthreads();
  if (t == 0) {
    float mm = -1e30f;
    for (int j = 0; j < OUTD; ++j) mm = fmaxf(mm, red[j]);
    float s = 0.f;
    for (int j = 0; j < OUTD; ++j) s += __expf(red[j] - mm);
    float l = logf(s);
    for (int j = 0; j < OUTD; ++j) out[g * OUTD + j] = red[j] - mm - l;
  }
}

extern "C" void kernel_launch(void* const* d_in, const int* in_sizes, int n_in, void* d_out,
                              int out_size, void* d_ws, size_t ws_size, hipStream_t stream) {
  const float* x = (const float*)d_in[0];
  const int* ei = (const int*)d_in[1];
  const int* batch = (const int*)d_in[2];
  const float* gcnW = (const float*)d_in[3];
  const float* gcnB = (const float*)d_in[4];
  const float* gatW = (const float*)d_in[5];
  const float* attS = (const float*)d_in[6];
  const float* attD = (const float*)d_in[7];
  const float* gatB = (const float*)d_in[8];
  const float* ecW1 = (const float*)d_in[9];
  const float* ecB1 = (const float*)d_in[10];
  const float* ecW2 = (const float*)d_in[11];
  const float* ecB2 = (const float*)d_in[12];
  const float* ginW1 = (const float*)d_in[13];
  const float* ginB1 = (const float*)d_in[14];
  const float* ginW2 = (const float*)d_in[15];
  const float* ginB2 = (const float*)d_in[16];
  const float* gtW1 = (const float*)d_in[17];
  const float* gtB1 = (const float*)d_in[18];
  const float* gtW2 = (const float*)d_in[19];
  const float* gtB2 = (const float*)d_in[20];
  const float* fcW = (const float*)d_in[21];
  const float* fcB = (const float*)d_in[22];

  const int N = in_sizes[0] / H;
  const int E = in_sizes[1] / 2;
  const int G = out_size / OUTD;
  const size_t NH = (size_t)N * H;

  auto align16 = [](char* p) { return (char*)(((uintptr_t)p + 15) & ~(uintptr_t)15); };
  char* p = (char*)d_ws;
  unsigned* hec = (unsigned*)p;      p += NH * 4;
  float* dinv = (float*)p;           p += (size_t)N * 4;
  float* asrc = (float*)p;           p += (size_t)4 * N * 4;
  float* adst = (float*)p;           p += (size_t)4 * N * 4;
  float* gate = (float*)p;           p += (size_t)N * 4;
  int* starts = (int*)p;             p += (size_t)(G + 1) * 4;
  int* cnt = (int*)p;                p += (size_t)N * 4;
  int* row_ptr = (int*)p;            p += (size_t)(N + 1) * 4;
  int* cursor = (int*)p;             p += (size_t)N * 4;
  int* csr_src = (int*)p;            p += (size_t)E * 4;
  int* csr_dst = (int*)p;            p += (size_t)E * 4;
  p = align16(p);
  unsigned short* WT = (unsigned short*)p;  p += (size_t)8 * 16384 * 2;
  p = align16(p);
  unsigned short* T0 = (unsigned short*)p;  p += NH * 2;
  p = align16(p);
  unsigned short* T1 = (unsigned short*)p;  p += NH * 2;
  p = align16(p);
  unsigned short* T2 = (unsigned short*)p;  p += NH * 2;
  p = align16(p);
  unsigned short* msgbuf = (unsigned short*)p;
  size_t needed_split = (size_t)(p - (char*)d_ws) + (size_t)E * H * 2 + 64;
  const bool use_split = ws_size >= needed_split;

  const unsigned short* gcnT = WT;
  const unsigned short* gatT = WT + 16384;
  const unsigned short* WaT = WT + 2 * 16384;
  const unsigned short* WbT = WT + 3 * 16384;
  const unsigned short* W2T = WT + 4 * 16384;
  const unsigned short* gin1T = WT + 5 * 16384;
  const unsigned short* gin2T = WT + 6 * 16384;
  const unsigned short* gt1T = WT + 7 * 16384;

  const int gN = (N + 255) / 256;
  const int gNH = (int)((NH + 255) / 256);
  const int gE = (E + 255) / 256;
  const int gDense = (N + 63) / 64;
  const int gW4 = (N + 3) / 4;

  // ---- prep + CSR ----
  prep_w<<<(8 * 16384 + 255) / 256, 256, 0, stream>>>(gcnW, gatW, ecW1, ecW2, ginW1, ginW2,
                                                      gtW1, WT);
  zero_int<<<gN, 256, 0, stream>>>(cnt, N);
  csr_count<<<gE, 256, 0, stream>>>(ei, cnt, E);
  scan50k<<<1, 1024, 0, stream>>>(cnt, row_ptr, N);
  copy_int<<<gN, 256, 0, stream>>>(row_ptr, cursor, N);
  csr_fill<<<gE, 256, 0, stream>>>(ei, cursor, csr_src, csr_dst, E);
  dinv_kernel<<<gN, 256, 0, stream>>>(row_ptr, dinv, N);

  // ---- GCN ----
  dense_mfma<0, 0, 0><<<gDense, 256, 0, stream>>>(x, gcnT, nullptr, T0, N);
  gcn_gather<<<gW4, 256, 0, stream>>>(T0, dinv, row_ptr, csr_src, gcnB, T1, N);

  // ---- GAT ----
  dense_mfma<1, 0, 0><<<gDense, 256, 0, stream>>>(T1, gatT, nullptr, T2, N);
  att_pre<<<(N * 4 + 255) / 256, 256, 0, stream>>>(T2, attS, attD, asrc, adst, N);
  gat_gather<<<gW4, 256, 0, stream>>>(T2, asrc, adst, row_ptr, csr_src, gatB, T0, N);

  // ---- EdgeConv ----
  dense_dual<<<gDense, 256, 0, stream>>>(T0, WaT, WbT, ecB1, T1, T2, N);
  fill_u32<<<gNH, 256, 0, stream>>>(hec, 0x80000000u, NH);  // enc(0.0): folds relu + isolated
  if (use_split) {
    ec_msg<<<2048, 256, 0, stream>>>(T1, T2, csr_src, csr_dst, msgbuf, E);
    edgeconv_stream<<<2048, 256, 0, stream>>>(msgbuf, csr_dst, W2T, ecB2, hec, E);
  } else {
    edgeconv_tile<<<2048, 256, 0, stream>>>(T1, T2, csr_src, csr_dst, W2T, ecB2, hec, E);
  }
  ec_decode<<<(int)((NH / 2 + 255) / 256), 256, 0, stream>>>(hec, T0, NH / 2);

  // ---- GIN ----
  gin_gather<<<gW4, 256, 0, stream>>>(T0, row_ptr, csr_src, T1, N);
  dense_chain<<<gDense, 256, 0, stream>>>(T1, gin1T, ginB1, gin2T, ginB2, T2, N);  // h4 = T2

  // ---- gating + pooling ----
  dense_gate<<<gDense, 256, 0, stream>>>(T2, gt1T, gtB1, gtW2, gtB2, gate, N);
  starts_kernel<<<gN, 256, 0, stream>>>(batch, starts, N, G);
  pool_fused<<<G, 256, 0, stream>>>(gate, T2, starts, fcW, fcB, (float*)d_out);
}

// Round 10
// 808.956 us; speedup vs baseline: 1.0437x; 1.0029x over previous
//
#include <hip/hip_runtime.h>

#define H 128
#define OUTD 10

typedef short bf16x8 __attribute__((ext_vector_type(8)));
typedef float f32x4 __attribute__((ext_vector_type(4)));

// ---------- bf16 helpers ----------
__device__ __forceinline__ unsigned short f2bf(float x) {
  unsigned u = __float_as_uint(x);
  u += 0x7fffu + ((u >> 16) & 1u);  // RNE
  return (unsigned short)(u >> 16);
}
__device__ __forceinline__ unsigned pack2bf(float a, float b) {
  return (unsigned)f2bf(a) | ((unsigned)f2bf(b) << 16);
}
__device__ __forceinline__ float bf2f(unsigned short u) {
  return __uint_as_float(((unsigned)u) << 16);
}
__device__ __forceinline__ float bflo(unsigned u) { return __uint_as_float(u << 16); }
__device__ __forceinline__ float bfhi(unsigned u) { return __uint_as_float(u & 0xffff0000u); }
__device__ __forceinline__ unsigned addrelu2(unsigned a, unsigned b) {
  return pack2bf(fmaxf(bflo(a) + bflo(b), 0.f), fmaxf(bfhi(a) + bfhi(b), 0.f));
}

// ---------- ordered-float encoding for atomic max ----------
__device__ __forceinline__ unsigned fenc(float x) {
  unsigned u = __float_as_uint(x);
  return (u & 0x80000000u) ? ~u : (u | 0x80000000u);
}
__device__ __forceinline__ float fdec(unsigned u) {
  u = (u & 0x80000000u) ? (u & 0x7fffffffu) : ~u;
  return __uint_as_float(u);
}

// ---------- weight prep: 8 matrices -> bf16 transposed [j][k] ----------
__global__ void prep_w(const float* __restrict__ gcnW, const float* __restrict__ gatW,
                       const float* __restrict__ ecW1, const float* __restrict__ ecW2,
                       const float* __restrict__ ginW1, const float* __restrict__ ginW2,
                       const float* __restrict__ gtW1, unsigned short* __restrict__ WT) {
  int f = blockIdx.x * 256 + threadIdx.x;
  if (f >= 8 * 16384) return;
  int m = f >> 14, idx = f & 16383;
  int j = idx >> 7, k = idx & 127;
  int src = k * 128 + j;
  float v;
  switch (m) {
    case 0: v = gcnW[src]; break;
    case 1: v = gatW[src]; break;
    case 2: v = ecW1[src] - ecW1[16384 + src]; break;  // Wa = top - bot
    case 3: v = ecW1[16384 + src]; break;              // Wb
    case 4: v = ecW2[src]; break;
    case 5: v = ginW1[src]; break;
    case 6: v = ginW2[src]; break;
    default: v = gtW1[src]; break;
  }
  WT[f] = f2bf(v);
}

// ---------- MFMA dense [n,128]@[128,128], W^T bf16 in global (L1), bf16 out ----------
template <int IN_BF, int RELU, int BIAS>
__global__ __launch_bounds__(256) void dense_mfma(const void* __restrict__ Xv,
                                                  const unsigned short* __restrict__ WT,
                                                  const float* __restrict__ bias,
                                                  unsigned short* __restrict__ Y, int n) {
  __shared__ unsigned short tile[64][136];
  const int tid = threadIdx.x, lane = tid & 63, wave = tid >> 6;
  const int jl = lane & 15, kg = lane >> 4;
  const int base = blockIdx.x * 64;
  if (base >= n) return;
  const int nr = min(64, n - base);
  if (IN_BF) {
    const uint4* X4 = (const uint4*)Xv;
#pragma unroll
    for (int it = 0; it < 4; ++it) {
      int f = it * 256 + tid, r = f >> 4, q = f & 15;
      if (r < nr) *(uint4*)&tile[r][q * 8] = X4[(size_t)(base + r) * 16 + q];
    }
  } else {
    const float* X = (const float*)Xv;
#pragma unroll
    for (int it = 0; it < 16; ++it) {
      int f = it * 256 + tid, r = f >> 6, kp = f & 63;
      if (r < nr) {
        float2 v = *(const float2*)&X[(size_t)(base + r) * H + 2 * kp];
        *(unsigned*)&tile[r][2 * kp] = pack2bf(v.x, v.y);
      }
    }
  }
  __syncthreads();
  bf16x8 afrag[4];
#pragma unroll
  for (int kk = 0; kk < 4; ++kk)
    afrag[kk] = *(const bf16x8*)&tile[wave * 16 + jl][kk * 32 + kg * 8];
  f32x4 acc[8];
#pragma unroll
  for (int jt = 0; jt < 8; ++jt) {
    f32x4 c = {0.f, 0.f, 0.f, 0.f};
#pragma unroll
    for (int kk = 0; kk < 4; ++kk) {
      bf16x8 bf = *(const bf16x8*)&WT[(size_t)(jt * 16 + jl) * H + kk * 32 + kg * 8];
      c = __builtin_amdgcn_mfma_f32_16x16x32_bf16(afrag[kk], bf, c, 0, 0, 0);
    }
    if (BIAS) {
      float bb = bias[jt * 16 + jl];
#pragma unroll
      for (int r = 0; r < 4; ++r) c[r] += bb;
    }
    if (RELU) {
#pragma unroll
      for (int r = 0; r < 4; ++r) c[r] = fmaxf(c[r], 0.f);
    }
    acc[jt] = c;
  }
  __syncthreads();
#pragma unroll
  for (int jt = 0; jt < 8; ++jt)
#pragma unroll
    for (int r = 0; r < 4; ++r) tile[wave * 16 + kg * 4 + r][jt * 16 + jl] = f2bf(acc[jt][r]);
  __syncthreads();
#pragma unroll
  for (int it = 0; it < 4; ++it) {
    int f = it * 256 + tid, r = f >> 4, q = f & 15;
    if (r < nr) *(uint4*)&Y[(size_t)(base + r) * H + q * 8] = *(const uint4*)&tile[r][q * 8];
  }
}

// ---------- dual dense: Y1 = X@W1, Y2 = X@W2 + b2 (shared X staging) ----------
__global__ __launch_bounds__(256) void dense_dual(const unsigned short* __restrict__ X,
                                                  const unsigned short* __restrict__ WT1,
                                                  const unsigned short* __restrict__ WT2,
                                                  const float* __restrict__ bias2,
                                                  unsigned short* __restrict__ Y1,
                                                  unsigned short* __restrict__ Y2, int n) {
  __shared__ unsigned short tile[64][136];
  const int tid = threadIdx.x, lane = tid & 63, wave = tid >> 6;
  const int jl = lane & 15, kg = lane >> 4;
  const int base = blockIdx.x * 64;
  if (base >= n) return;
  const int nr = min(64, n - base);
  const uint4* X4 = (const uint4*)X;
#pragma unroll
  for (int it = 0; it < 4; ++it) {
    int f = it * 256 + tid, r = f >> 4, q = f & 15;
    if (r < nr) *(uint4*)&tile[r][q * 8] = X4[(size_t)(base + r) * 16 + q];
  }
  __syncthreads();
  bf16x8 afrag[4];
#pragma unroll
  for (int kk = 0; kk < 4; ++kk)
    afrag[kk] = *(const bf16x8*)&tile[wave * 16 + jl][kk * 32 + kg * 8];
  f32x4 acc[8];
#pragma unroll
  for (int jt = 0; jt < 8; ++jt) {
    f32x4 c = {0.f, 0.f, 0.f, 0.f};
#pragma unroll
    for (int kk = 0; kk < 4; ++kk) {
      bf16x8 bf = *(const bf16x8*)&WT1[(size_t)(jt * 16 + jl) * H + kk * 32 + kg * 8];
      c = __builtin_amdgcn_mfma_f32_16x16x32_bf16(afrag[kk], bf, c, 0, 0, 0);
    }
    acc[jt] = c;
  }
  __syncthreads();
#pragma unroll
  for (int jt = 0; jt < 8; ++jt)
#pragma unroll
    for (int r = 0; r < 4; ++r) tile[wave * 16 + kg * 4 + r][jt * 16 + jl] = f2bf(acc[jt][r]);
  __syncthreads();
#pragma unroll
  for (int it = 0; it < 4; ++it) {
    int f = it * 256 + tid, r = f >> 4, q = f & 15;
    if (r < nr) *(uint4*)&Y1[(size_t)(base + r) * H + q * 8] = *(const uint4*)&tile[r][q * 8];
  }
  __syncthreads();
#pragma unroll
  for (int jt = 0; jt < 8; ++jt) {
    f32x4 c = {0.f, 0.f, 0.f, 0.f};
#pragma unroll
    for (int kk = 0; kk < 4; ++kk) {
      bf16x8 bf = *(const bf16x8*)&WT2[(size_t)(jt * 16 + jl) * H + kk * 32 + kg * 8];
      c = __builtin_amdgcn_mfma_f32_16x16x32_bf16(afrag[kk], bf, c, 0, 0, 0);
    }
    float bb = bias2[jt * 16 + jl];
#pragma unroll
    for (int r = 0; r < 4; ++r) c[r] += bb;
    acc[jt] = c;
  }
  __syncthreads();
#pragma unroll
  for (int jt = 0; jt < 8; ++jt)
#pragma unroll
    for (int r = 0; r < 4; ++r) tile[wave * 16 + kg * 4 + r][jt * 16 + jl] = f2bf(acc[jt][r]);
  __syncthreads();
#pragma unroll
  for (int it = 0; it < 4; ++it) {
    int f = it * 256 + tid, r = f >> 4, q = f & 15;
    if (r < nr) *(uint4*)&Y2[(size_t)(base + r) * H + q * 8] = *(const uint4*)&tile[r][q * 8];
  }
}

// ---------- chained dense (GIN): Y = relu(relu(X@W1+b1)@W2+b2) ----------
__global__ __launch_bounds__(256) void dense_chain(const unsigned short* __restrict__ X,
                                                   const unsigned short* __restrict__ WT1,
                                                   const float* __restrict__ b1,
                                                   const unsigned short* __restrict__ WT2,
                                                   const float* __restrict__ b2,
                                                   unsigned short* __restrict__ Y, int n) {
  __shared__ unsigned short tile[64][136];
  const int tid = threadIdx.x, lane = tid & 63, wave = tid >> 6;
  const int jl = lane & 15, kg = lane >> 4;
  const int base = blockIdx.x * 64;
  if (base >= n) return;
  const int nr = min(64, n - base);
  const uint4* X4 = (const uint4*)X;
#pragma unroll
  for (int it = 0; it < 4; ++it) {
    int f = it * 256 + tid, r = f >> 4, q = f & 15;
    if (r < nr) *(uint4*)&tile[r][q * 8] = X4[(size_t)(base + r) * 16 + q];
  }
  __syncthreads();
  bf16x8 af[4];
#pragma unroll
  for (int kk = 0; kk < 4; ++kk) af[kk] = *(const bf16x8*)&tile[wave * 16 + jl][kk * 32 + kg * 8];
  f32x4 acc[8];
#pragma unroll
  for (int jt = 0; jt < 8; ++jt) {
    f32x4 c = {0.f, 0.f, 0.f, 0.f};
#pragma unroll
    for (int kk = 0; kk < 4; ++kk) {
      bf16x8 bf = *(const bf16x8*)&WT1[(size_t)(jt * 16 + jl) * H + kk * 32 + kg * 8];
      c = __builtin_amdgcn_mfma_f32_16x16x32_bf16(af[kk], bf, c, 0, 0, 0);
    }
    float bb = b1[jt * 16 + jl];
#pragma unroll
    for (int r = 0; r < 4; ++r) c[r] = fmaxf(c[r] + bb, 0.f);
    acc[jt] = c;
  }
  __syncthreads();
#pragma unroll
  for (int jt = 0; jt < 8; ++jt)
#pragma unroll
    for (int r = 0; r < 4; ++r) tile[wave * 16 + kg * 4 + r][jt * 16 + jl] = f2bf(acc[jt][r]);
  __syncthreads();
#pragma unroll
  for (int kk = 0; kk < 4; ++kk) af[kk] = *(const bf16x8*)&tile[wave * 16 + jl][kk * 32 + kg * 8];
#pragma unroll
  for (int jt = 0; jt < 8; ++jt) {
    f32x4 c = {0.f, 0.f, 0.f, 0.f};
#pragma unroll
    for (int kk = 0; kk < 4; ++kk) {
      bf16x8 bf = *(const bf16x8*)&WT2[(size_t)(jt * 16 + jl) * H + kk * 32 + kg * 8];
      c = __builtin_amdgcn_mfma_f32_16x16x32_bf16(af[kk], bf, c, 0, 0, 0);
    }
    float bb = b2[jt * 16 + jl];
#pragma unroll
    for (int r = 0; r < 4; ++r) c[r] = fmaxf(c[r] + bb, 0.f);
    acc[jt] = c;
  }
  __syncthreads();
#pragma unroll
  for (int jt = 0; jt < 8; ++jt)
#pragma unroll
    for (int r = 0; r < 4; ++r) tile[wave * 16 + kg * 4 + r][jt * 16 + jl] = f2bf(acc[jt][r]);
  __syncthreads();
#pragma unroll
  for (int it = 0; it < 4; ++it) {
    int f = it * 256 + tid, r = f >> 4, q = f & 15;
    if (r < nr) *(uint4*)&Y[(size_t)(base + r) * H + q * 8] = *(const uint4*)&tile[r][q * 8];
  }
}

// ---------- gate dense: gate = relu(X@W1+b1) . w2 + b2 ----------
__global__ __launch_bounds__(256) void dense_gate(const unsigned short* __restrict__ X,
                                                  const unsigned short* __restrict__ WT,
                                                  const float* __restrict__ b1,
                                                  const float* __restrict__ w2,
                                                  const float* __restrict__ b2,
                                                  float* __restrict__ gate, int n) {
  __shared__ unsigned short tile[64][136];
  const int tid = threadIdx.x, lane = tid & 63, wave = tid >> 6;
  const int jl = lane & 15, kg = lane >> 4;
  const int base = blockIdx.x * 64;
  if (base >= n) return;
  const int nr = min(64, n - base);
  const uint4* X4 = (const uint4*)X;
#pragma unroll
  for (int it = 0; it < 4; ++it) {
    int f = it * 256 + tid, r = f >> 4, q = f & 15;
    if (r < nr) *(uint4*)&tile[r][q * 8] = X4[(size_t)(base + r) * 16 + q];
  }
  __syncthreads();
  bf16x8 af[4];
#pragma unroll
  for (int kk = 0; kk < 4; ++kk) af[kk] = *(const bf16x8*)&tile[wave * 16 + jl][kk * 32 + kg * 8];
  float p0 = 0.f, p1 = 0.f, p2 = 0.f, p3 = 0.f;
#pragma unroll
  for (int jt = 0; jt < 8; ++jt) {
    f32x4 c = {0.f, 0.f, 0.f, 0.f};
#pragma unroll
    for (int kk = 0; kk < 4; ++kk) {
      bf16x8 bf = *(const bf16x8*)&WT[(size_t)(jt * 16 + jl) * H + kk * 32 + kg * 8];
      c = __builtin_amdgcn_mfma_f32_16x16x32_bf16(af[kk], bf, c, 0, 0, 0);
    }
    float bb = b1[jt * 16 + jl];
    float wv = w2[jt * 16 + jl];
    p0 = fmaf(fmaxf(c[0] + bb, 0.f), wv, p0);
    p1 = fmaf(fmaxf(c[1] + bb, 0.f), wv, p1);
    p2 = fmaf(fmaxf(c[2] + bb, 0.f), wv, p2);
    p3 = fmaf(fmaxf(c[3] + bb, 0.f), wv, p3);
  }
#pragma unroll
  for (int off = 1; off <= 8; off <<= 1) {
    p0 += __shfl_xor(p0, off);
    p1 += __shfl_xor(p1, off);
    p2 += __shfl_xor(p2, off);
    p3 += __shfl_xor(p3, off);
  }
  if (jl == 0) {
    float bb2 = b2[0];
    int row = wave * 16 + kg * 4;
    if (row + 0 < nr) gate[base + row + 0] = p0 + bb2;
    if (row + 1 < nr) gate[base + row + 1] = p1 + bb2;
    if (row + 2 < nr) gate[base + row + 2] = p2 + bb2;
    if (row + 3 < nr) gate[base + row + 3] = p3 + bb2;
  }
}

// ---------- CSR build ----------
__global__ void zero_int(int* p, int n) {
  int i = blockIdx.x * 256 + threadIdx.x;
  if (i < n) p[i] = 0;
}
__global__ void csr_count(const int* __restrict__ ei, int* __restrict__ cnt, int E) {
  int e = blockIdx.x * 256 + threadIdx.x;
  if (e < E) atomicAdd(&cnt[ei[(size_t)E + e]], 1);
}
__global__ __launch_bounds__(1024) void scan50k(const int* __restrict__ cnt,
                                                int* __restrict__ row_ptr, int n) {
  __shared__ int ls[1024];
  int t = threadIdx.x;
  int chunk = (n + 1023) >> 10;
  int a = t * chunk;
  if (a > n) a = n;
  int b = a + chunk;
  if (b > n) b = n;
  int s = 0;
  for (int i = a; i < b; ++i) s += cnt[i];
  ls[t] = s;
  __syncthreads();
  for (int off = 1; off < 1024; off <<= 1) {
    int v = (t >= off) ? ls[t - off] : 0;
    __syncthreads();
    ls[t] += v;
    __syncthreads();
  }
  int run = (t > 0) ? ls[t - 1] : 0;
  for (int i = a; i < b; ++i) {
    row_ptr[i] = run;
    run += cnt[i];
  }
  if (t == 1023) row_ptr[n] = ls[1023];
}
__global__ void copy_int(const int* __restrict__ a, int* __restrict__ b, int n) {
  int i = blockIdx.x * 256 + threadIdx.x;
  if (i < n) b[i] = a[i];
}
__global__ void csr_fill(const int* __restrict__ ei, int* __restrict__ cursor,
                         int* __restrict__ csr_src, int* __restrict__ csr_dst, int E) {
  int e = blockIdx.x * 256 + threadIdx.x;
  if (e >= E) return;
  int s = ei[e], d = ei[(size_t)E + e];
  int p = atomicAdd(&cursor[d], 1);
  csr_src[p] = s;
  csr_dst[p] = d;
}
__global__ void dinv_kernel(const int* __restrict__ row_ptr, float* __restrict__ dinv, int n) {
  int i = blockIdx.x * 256 + threadIdx.x;
  if (i < n) dinv[i] = rsqrtf((float)(1 + row_ptr[i + 1] - row_ptr[i]));
}
__global__ void fill_u32(unsigned* p, unsigned v, size_t n) {
  size_t i = (size_t)blockIdx.x * 256 + threadIdx.x;
  if (i < n) p[i] = v;
}

// ---------- GCN gather: wave per node, 8x unrolled ----------
__global__ __launch_bounds__(256) void gcn_gather(const unsigned short* __restrict__ h,
                                                  const float* __restrict__ dinv,
                                                  const int* __restrict__ row_ptr,
                                                  const int* __restrict__ csr_src,
                                                  const float* __restrict__ bias,
                                                  unsigned short* __restrict__ out, int n) {
  int node = blockIdx.x * 4 + (threadIdx.x >> 6);
  int lane = threadIdx.x & 63;
  if (node >= n) return;
  const unsigned* hu = (const unsigned*)h;
  float di = dinv[node];
  unsigned v = hu[(size_t)node * 64 + lane];
  float t0 = bflo(v) * di, t1 = bfhi(v) * di;
  int a = row_ptr[node], b = row_ptr[node + 1];
  int e = a;
  for (; e + 8 <= b; e += 8) {
    int sx[8];
#pragma unroll
    for (int i = 0; i < 8; ++i) sx[i] = csr_src[e + i];
    unsigned w[8];
    float dd[8];
#pragma unroll
    for (int i = 0; i < 8; ++i) w[i] = hu[(size_t)sx[i] * 64 + lane];
#pragma unroll
    for (int i = 0; i < 8; ++i) dd[i] = dinv[sx[i]];
#pragma unroll
    for (int i = 0; i < 8; ++i) {
      t0 = fmaf(bflo(w[i]), dd[i], t0);
      t1 = fmaf(bfhi(w[i]), dd[i], t1);
    }
  }
  for (; e < b; ++e) {
    int s = csr_src[e];
    float ds = dinv[s];
    unsigned w = hu[(size_t)s * 64 + lane];
    t0 = fmaf(bflo(w), ds, t0);
    t1 = fmaf(bfhi(w), ds, t1);
  }
  float y0 = fmaxf(fmaf(t0, di, bias[lane * 2]), 0.f);
  float y1 = fmaxf(fmaf(t1, di, bias[lane * 2 + 1]), 0.f);
  ((unsigned*)out)[(size_t)node * 64 + lane] = pack2bf(y0, y1);
}

__global__ void att_pre(const unsigned short* __restrict__ g, const float* __restrict__ attS,
                        const float* __restrict__ attD, float* __restrict__ asrc,
                        float* __restrict__ adst, int n) {
  int t = blockIdx.x * 256 + threadIdx.x;
  if (t >= n * 4) return;
  int i = t >> 2, hd = t & 3;
  const unsigned* gr = (const unsigned*)(g + (size_t)i * H + hd * 32);
  float s1 = 0.f, s2 = 0.f;
#pragma unroll
  for (int p = 0; p < 16; ++p) {
    unsigned u = gr[p];
    float a = bflo(u), b = bfhi(u);
    s1 = fmaf(a, attS[hd * 32 + 2 * p], fmaf(b, attS[hd * 32 + 2 * p + 1], s1));
    s2 = fmaf(a, attD[hd * 32 + 2 * p], fmaf(b, attD[hd * 32 + 2 * p + 1], s2));
  }
  asrc[t] = s1;
  adst[t] = s2;
}

__device__ __forceinline__ float lrelu_exp(float v) {
  v = v > 0.f ? v : 0.2f * v;
  return __expf(v);
}

// ---------- GAT gather: wave per node, 8x unrolled ----------
__global__ __launch_bounds__(256) void gat_gather(const unsigned short* __restrict__ g,
                                                  const float* __restrict__ asrc,
                                                  const float* __restrict__ adst,
                                                  const int* __restrict__ row_ptr,
                                                  const int* __restrict__ csr_src,
                                                  const float* __restrict__ bias,
                                                  unsigned short* __restrict__ out, int n) {
  int node = blockIdx.x * 4 + (threadIdx.x >> 6);
  int lane = threadIdx.x & 63;
  if (node >= n) return;
  const int hd = lane >> 4;
  const unsigned* gu = (const unsigned*)g;
  float adc = adst[node * 4 + hd];
  float w = lrelu_exp(asrc[node * 4 + hd] + adc);
  unsigned u = gu[(size_t)node * 64 + lane];
  float acc0 = w * bflo(u), acc1 = w * bfhi(u), wsum = w;
  int a = row_ptr[node], b = row_ptr[node + 1];
  int e = a;
  for (; e + 8 <= b; e += 8) {
    int sx[8];
#pragma unroll
    for (int i = 0; i < 8; ++i) sx[i] = csr_src[e + i];
    unsigned uu[8];
#pragma unroll
    for (int i = 0; i < 8; ++i) uu[i] = gu[(size_t)sx[i] * 64 + lane];
    float ww[8];
#pragma unroll
    for (int i = 0; i < 8; ++i) ww[i] = lrelu_exp(asrc[sx[i] * 4 + hd] + adc);
#pragma unroll
    for (int i = 0; i < 8; ++i) {
      acc0 = fmaf(ww[i], bflo(uu[i]), acc0);
      acc1 = fmaf(ww[i], bfhi(uu[i]), acc1);
      wsum += ww[i];
    }
  }
  for (; e < b; ++e) {
    int s = csr_src[e];
    unsigned us = gu[(size_t)s * 64 + lane];
    float we = lrelu_exp(asrc[s * 4 + hd] + adc);
    acc0 = fmaf(we, bflo(us), acc0);
    acc1 = fmaf(we, bfhi(us), acc1);
    wsum += we;
  }
  float inv = 1.f / (wsum + 1e-16f);
  float r0 = acc0 * inv + bias[2 * lane];
  float r1 = acc1 * inv + bias[2 * lane + 1];
  r0 = r0 > 0.f ? r0 : expm1f(r0);
  r1 = r1 > 0.f ? r1 : expm1f(r1);
  ((unsigned*)out)[(size_t)node * 64 + lane] = pack2bf(r0, r1);
}

// ---------- EdgeConv: wave-per-16-edges, barrier-free, LDS-free, direct fragment gather ----------
__global__ __launch_bounds__(256) void edgeconv_wave(const unsigned short* __restrict__ A,
                                                     const unsigned short* __restrict__ Bm,
                                                     const int* __restrict__ csr_src,
                                                     const int* __restrict__ csr_dst,
                                                     const unsigned short* __restrict__ W2T,
                                                     const float* __restrict__ b2,
                                                     unsigned* __restrict__ hec, int E) {
  const int lane = threadIdx.x & 63;
  const int jl = lane & 15, kg = lane >> 4;
  const int wid0 = blockIdx.x * 4 + (threadIdx.x >> 6);
  const int nw = gridDim.x * 4;
  float b2v[8];
#pragma unroll
  for (int jt = 0; jt < 8; ++jt) b2v[jt] = b2[jt * 16 + jl];
  const int ntile = (E + 15) >> 4;

  for (int t = wid0; t < ntile; t += nw) {
    const int base = t << 4;
    // --- A-fragment: lane owns edge-row (base+jl), k-chunks kk*32+kg*8 ---
    const int myrow = base + jl;
    uint4 va[4], vb[4];
    if (myrow < E) {
      int s = csr_src[myrow], d = csr_dst[myrow];
      const unsigned short* Arow = A + (size_t)d * H + kg * 8;
      const unsigned short* Brow = Bm + (size_t)s * H + kg * 8;
#pragma unroll
      for (int kk = 0; kk < 4; ++kk) {
        va[kk] = *(const uint4*)(Arow + kk * 32);
        vb[kk] = *(const uint4*)(Brow + kk * 32);
      }
    } else {
#pragma unroll
      for (int kk = 0; kk < 4; ++kk) va[kk] = vb[kk] = {0u, 0u, 0u, 0u};
    }
    // --- epilogue dsts for this lane's C rows (base + kg*4 + r) ---
    int d0, d1, d2, d3;
    {
      int rb = base + kg * 4;
      if (rb + 3 < E) {
        int4 q = *(const int4*)(csr_dst + rb);
        d0 = q.x;
        d1 = q.y;
        d2 = q.z;
        d3 = q.w;
      } else {
        d0 = (rb + 0 < E) ? csr_dst[rb + 0] : -1;
        d1 = (rb + 1 < E) ? csr_dst[rb + 1] : -1;
        d2 = (rb + 2 < E) ? csr_dst[rb + 2] : -1;
        d3 = (rb + 3 < E) ? csr_dst[rb + 3] : -1;
      }
    }
    // --- pack relu(a+b) to bf16 fragments ---
    bf16x8 af[4];
#pragma unroll
    for (int kk = 0; kk < 4; ++kk) {
      uint4 o;
      o.x = addrelu2(va[kk].x, vb[kk].x);
      o.y = addrelu2(va[kk].y, vb[kk].y);
      o.z = addrelu2(va[kk].z, vb[kk].z);
      o.w = addrelu2(va[kk].w, vb[kk].w);
      af[kk] = *(bf16x8*)&o;
    }
    // --- 32 MFMA + per-jt register run-merge + fire-and-forget atomics ---
#pragma unroll
    for (int jt = 0; jt < 8; ++jt) {
      f32x4 c = {0.f, 0.f, 0.f, 0.f};
#pragma unroll
      for (int kk = 0; kk < 4; ++kk) {
        bf16x8 wf = *(const bf16x8*)&W2T[(size_t)(jt * 16 + jl) * H + kk * 32 + kg * 8];
        c = __builtin_amdgcn_mfma_f32_16x16x32_bf16(af[kk], wf, c, 0, 0, 0);
      }
      const int col = jt * 16 + jl;
      int cd = d0;
      float m = c[0];
      if (d1 != cd) {
        if (cd >= 0) atomicMax(&hec[(size_t)cd * H + col], fenc(m + b2v[jt]));
        cd = d1;
        m = c[1];
      } else
        m = fmaxf(m, c[1]);
      if (d2 != cd) {
        if (cd >= 0) atomicMax(&hec[(size_t)cd * H + col], fenc(m + b2v[jt]));
        cd = d2;
        m = c[2];
      } else
        m = fmaxf(m, c[2]);
      if (d3 != cd) {
        if (cd >= 0) atomicMax(&hec[(size_t)cd * H + col], fenc(m + b2v[jt]));
        cd = d3;
        m = c[3];
      } else
        m = fmaxf(m, c[3]);
      if (cd >= 0) atomicMax(&hec[(size_t)cd * H + col], fenc(m + b2v[jt]));
    }
  }
}

// ---------- decode hec (ordered u32) -> bf16 rows ----------
__global__ void ec_decode(const unsigned* __restrict__ hec, unsigned short* __restrict__ out,
                          size_t half) {
  size_t i = (size_t)blockIdx.x * 256 + threadIdx.x;
  if (i < half) {
    uint2 v = *(const uint2*)&hec[i * 2];
    ((unsigned*)out)[i] = pack2bf(fdec(v.x), fdec(v.y));
  }
}

// ---------- GIN gather: bf16 input, wave per node, 8x unrolled ----------
__global__ __launch_bounds__(256) void gin_gather(const unsigned short* __restrict__ h,
                                                  const int* __restrict__ row_ptr,
                                                  const int* __restrict__ csr_src,
                                                  unsigned short* __restrict__ out, int n) {
  int node = blockIdx.x * 4 + (threadIdx.x >> 6);
  int lane = threadIdx.x & 63;
  if (node >= n) return;
  const unsigned* hu = (const unsigned*)h;
  unsigned v = hu[(size_t)node * 64 + lane];
  float t0 = bflo(v), t1 = bfhi(v);
  int a = row_ptr[node], b = row_ptr[node + 1];
  int e = a;
  for (; e + 8 <= b; e += 8) {
    int sx[8];
#pragma unroll
    for (int i = 0; i < 8; ++i) sx[i] = csr_src[e + i];
    unsigned w[8];
#pragma unroll
    for (int i = 0; i < 8; ++i) w[i] = hu[(size_t)sx[i] * 64 + lane];
#pragma unroll
    for (int i = 0; i < 8; ++i) {
      t0 += bflo(w[i]);
      t1 += bfhi(w[i]);
    }
  }
  for (; e < b; ++e) {
    int s = csr_src[e];
    unsigned w = hu[(size_t)s * 64 + lane];
    t0 += bflo(w);
    t1 += bfhi(w);
  }
  ((unsigned*)out)[(size_t)node * 64 + lane] = pack2bf(t0, t1);
}

// ---------- pooling ----------
__global__ void starts_kernel(const int* __restrict__ batch, int* __restrict__ starts, int n,
                              int G) {
  int i = blockIdx.x * 256 + threadIdx.x;
  if (i >= n) return;
  int b = batch[i];
  int bp = (i == 0) ? -1 : batch[i - 1];
  for (int g = bp + 1; g <= b; ++g) starts[g] = i;
  if (i == n - 1)
    for (int g = b + 1; g <= G; ++g) starts[g] = n;
}
__global__ __launch_bounds__(256) void pool_fused(float* __restrict__ gate,
                                                  const unsigned short* __restrict__ h4,
                                                  const int* __restrict__ starts,
                                                  const float* __restrict__ fcW,
                                                  const float* __restrict__ fcB,
                                                  float* __restrict__ out) {
  __shared__ float red[256];
  __shared__ float pl[128];
  int g = blockIdx.x, t = threadIdx.x;
  int s0 = starts[g], s1 = starts[g + 1];
  float m = -1e30f;
  for (int i = s0 + t; i < s1; i += 256) m = fmaxf(m, gate[i]);
  red[t] = m;
  __syncthreads();
  for (int off = 128; off; off >>= 1) {
    if (t < off) red[t] = fmaxf(red[t], red[t + off]);
    __syncthreads();
  }
  m = red[0];
  __syncthreads();
  float sm = 0.f;
  for (int i = s0 + t; i < s1; i += 256) {
    float ge = __expf(gate[i] - m);
    gate[i] = ge;
    sm += ge;
  }
  red[t] = sm;
  __syncthreads();
  for (int off = 128; off; off >>= 1) {
    if (t < off) red[t] += red[t + off];
    __syncthreads();
  }
  float inv = 1.f / (red[0] + 1e-16f);
  __syncthreads();
  int c = t & 127, half = t >> 7;
  float acc = 0.f;
  for (int i = s0 + half; i < s1; i += 2) acc = fmaf(gate[i], bf2f(h4[(size_t)i * H + c]), acc);
  red[t] = acc;
  __syncthreads();
  if (t < 128) pl[t] = (red[t] + red[t + 128]) * inv;
  __syncthreads();
  if (t < OUTD) {
    float o = fcB[t];
    for (int k = 0; k < 128; ++k) o = fmaf(pl[k], fcW[k * OUTD + t], o);
    red[t] = o;
  }
  __syncthreads();
  if (t == 0) {
    float mm = -1e30f;
    for (int j = 0; j < OUTD; ++j) mm = fmaxf(mm, red[j]);
    float s = 0.f;
    for (int j = 0; j < OUTD; ++j) s += __expf(red[j] - mm);
    float l = logf(s);
    for (int j = 0; j < OUTD; ++j) out[g * OUTD + j] = red[j] - mm - l;
  }
}

extern "C" void kernel_launch(void* const* d_in, const int* in_sizes, int n_in, void* d_out,
                              int out_size, void* d_ws, size_t ws_size, hipStream_t stream) {
  const float* x = (const float*)d_in[0];
  const int* ei = (const int*)d_in[1];
  const int* batch = (const int*)d_in[2];
  const float* gcnW = (const float*)d_in[3];
  const float* gcnB = (const float*)d_in[4];
  const float* gatW = (const float*)d_in[5];
  const float* attS = (const float*)d_in[6];
  const float* attD = (const float*)d_in[7];
  const float* gatB = (const float*)d_in[8];
  const float* ecW1 = (const float*)d_in[9];
  const float* ecB1 = (const float*)d_in[10];
  const float* ecW2 = (const float*)d_in[11];
  const float* ecB2 = (const float*)d_in[12];
  const float* ginW1 = (const float*)d_in[13];
  const float* ginB1 = (const float*)d_in[14];
  const float* ginW2 = (const float*)d_in[15];
  const float* ginB2 = (const float*)d_in[16];
  const float* gtW1 = (const float*)d_in[17];
  const float* gtB1 = (const float*)d_in[18];
  const float* gtW2 = (const float*)d_in[19];
  const float* gtB2 = (const float*)d_in[20];
  const float* fcW = (const float*)d_in[21];
  const float* fcB = (const float*)d_in[22];

  const int N = in_sizes[0] / H;
  const int E = in_sizes[1] / 2;
  const int G = out_size / OUTD;
  const size_t NH = (size_t)N * H;

  auto align16 = [](char* p) { return (char*)(((uintptr_t)p + 15) & ~(uintptr_t)15); };
  char* p = (char*)d_ws;
  unsigned* hec = (unsigned*)p;      p += NH * 4;
  float* dinv = (float*)p;           p += (size_t)N * 4;
  float* asrc = (float*)p;           p += (size_t)4 * N * 4;
  float* adst = (float*)p;           p += (size_t)4 * N * 4;
  float* gate = (float*)p;           p += (size_t)N * 4;
  int* starts = (int*)p;             p += (size_t)(G + 1) * 4;
  int* cnt = (int*)p;                p += (size_t)N * 4;
  int* row_ptr = (int*)p;            p += (size_t)(N + 1) * 4;
  int* cursor = (int*)p;             p += (size_t)N * 4;
  int* csr_src = (int*)p;            p += (size_t)E * 4;
  int* csr_dst = (int*)p;            p += (size_t)E * 4;
  p = align16(p);
  unsigned short* WT = (unsigned short*)p;  p += (size_t)8 * 16384 * 2;
  p = align16(p);
  unsigned short* T0 = (unsigned short*)p;  p += NH * 2;
  p = align16(p);
  unsigned short* T1 = (unsigned short*)p;  p += NH * 2;
  p = align16(p);
  unsigned short* T2 = (unsigned short*)p;  p += NH * 2;

  const unsigned short* gcnT = WT;
  const unsigned short* gatT = WT + 16384;
  const unsigned short* WaT = WT + 2 * 16384;
  const unsigned short* WbT = WT + 3 * 16384;
  const unsigned short* W2T = WT + 4 * 16384;
  const unsigned short* gin1T = WT + 5 * 16384;
  const unsigned short* gin2T = WT + 6 * 16384;
  const unsigned short* gt1T = WT + 7 * 16384;

  const int gN = (N + 255) / 256;
  const int gNH = (int)((NH + 255) / 256);
  const int gE = (E + 255) / 256;
  const int gDense = (N + 63) / 64;
  const int gW4 = (N + 3) / 4;

  // ---- prep + CSR ----
  prep_w<<<(8 * 16384 + 255) / 256, 256, 0, stream>>>(gcnW, gatW, ecW1, ecW2, ginW1, ginW2,
                                                      gtW1, WT);
  zero_int<<<gN, 256, 0, stream>>>(cnt, N);
  csr_count<<<gE, 256, 0, stream>>>(ei, cnt, E);
  scan50k<<<1, 1024, 0, stream>>>(cnt, row_ptr, N);
  copy_int<<<gN, 256, 0, stream>>>(row_ptr, cursor, N);
  csr_fill<<<gE, 256, 0, stream>>>(ei, cursor, csr_src, csr_dst, E);
  dinv_kernel<<<gN, 256, 0, stream>>>(row_ptr, dinv, N);

  // ---- GCN ----
  dense_mfma<0, 0, 0><<<gDense, 256, 0, stream>>>(x, gcnT, nullptr, T0, N);
  gcn_gather<<<gW4, 256, 0, stream>>>(T0, dinv, row_ptr, csr_src, gcnB, T1, N);

  // ---- GAT ----
  dense_mfma<1, 0, 0><<<gDense, 256, 0, stream>>>(T1, gatT, nullptr, T2, N);
  att_pre<<<(N * 4 + 255) / 256, 256, 0, stream>>>(T2, attS, attD, asrc, adst, N);
  gat_gather<<<gW4, 256, 0, stream>>>(T2, asrc, adst, row_ptr, csr_src, gatB, T0, N);

  // ---- EdgeConv ----
  dense_dual<<<gDense, 256, 0, stream>>>(T0, WaT, WbT, ecB1, T1, T2, N);
  fill_u32<<<gNH, 256, 0, stream>>>(hec, 0x80000000u, NH);  // enc(0.0): folds relu + isolated
  edgeconv_wave<<<2048, 256, 0, stream>>>(T1, T2, csr_src, csr_dst, W2T, ecB2, hec, E);
  ec_decode<<<(int)((NH / 2 + 255) / 256), 256, 0, stream>>>(hec, T0, NH / 2);

  // ---- GIN ----
  gin_gather<<<gW4, 256, 0, stream>>>(T0, row_ptr, csr_src, T1, N);
  dense_chain<<<gDense, 256, 0, stream>>>(T1, gin1T, ginB1, gin2T, ginB2, T2, N);  // h4 = T2

  // ---- gating + pooling ----
  dense_gate<<<gDense, 256, 0, stream>>>(T2, gt1T, gtB1, gtW2, gtB2, gate, N);
  starts_kernel<<<gN, 256, 0, stream>>>(batch, starts, N, G);
  pool_fused<<<G, 256, 0, stream>>>(gate, T2, starts, fcW, fcB, (float*)d_out);
}